// Round 18
// baseline (114.853 us; speedup 1.0000x reference)
//
#include <hip/hip_runtime.h>

#define D_MODEL 1024
#define NUM_HEADS 16
#define HEAD_DIM 64
#define BATCH 2
#define SEQ 2048
#define MTOT (BATCH * SEQ)   // 4096

typedef __attribute__((ext_vector_type(8))) short bf16x8;   // 8 bf16 in 4 VGPRs
typedef __attribute__((ext_vector_type(4))) short s16x4;
typedef __attribute__((ext_vector_type(4))) float f32x4;
typedef unsigned short u16;
typedef unsigned long long u64;

__device__ __forceinline__ u16 f2bf(float f) {
    unsigned u = __float_as_uint(f);
    return (u16)((u + 0x7FFFu + ((u >> 16) & 1u)) >> 16);   // RNE, finite data
}
__device__ __forceinline__ float bf2f(u16 v) {
    return __uint_as_float((unsigned)v << 16);
}

__device__ __forceinline__ unsigned cvt_pk_bf16(float lo, float hi) {
    unsigned r;
    asm volatile("v_cvt_pk_bf16_f32 %0, %1, %2" : "=v"(r) : "v"(lo), "v"(hi));
    return r;
}

#if __has_builtin(__builtin_amdgcn_exp2f)
#define EXP2(x) __builtin_amdgcn_exp2f(x)
#else
#define EXP2(x) exp2f(x)
#endif

#define GLOAD16(gp, lp) __builtin_amdgcn_global_load_lds(                      \
    (const __attribute__((address_space(1))) void*)(gp),                       \
    (__attribute__((address_space(3))) void*)(lp), 16, 0, 0)

// ---------------------------------------------------------------------------
// One merged fp32 -> bf16 cast: x | Wqkv | Wo into contiguous ws region.
// ---------------------------------------------------------------------------
__global__ __launch_bounds__(256)
void cast_all_kernel(const float* __restrict__ x,  const float* __restrict__ Wq,
                     const float* __restrict__ Wk, const float* __restrict__ Wv,
                     const float* __restrict__ Wo, u16* __restrict__ dst)
{
    const int i = blockIdx.x * 256 + threadIdx.x;   // 1048576 groups of 8
    const float* src;
    int j;
    if (i < 524288) { src = x; j = i; }
    else if (i < 917504) {
        const int k = i - 524288;
        const int z = k >> 17;
        src = (z == 0) ? Wq : (z == 1) ? Wk : Wv;
        j = k & 0x1FFFF;
    } else { src = Wo; j = i - 917504; }
    const float4* s = reinterpret_cast<const float4*>(src) + (size_t)j * 2;
    float4 a = s[0], b = s[1];
    u16 tmp[8] = {f2bf(a.x), f2bf(a.y), f2bf(a.z), f2bf(a.w),
                  f2bf(b.x), f2bf(b.y), f2bf(b.z), f2bf(b.w)};
    *reinterpret_cast<int4*>(dst + (size_t)i * 8) = *reinterpret_cast<int4*>(tmp);
}

// ---------------------------------------------------------------------------
// QKV GEMM, pipelined, 8-wave (round-15, unchanged): BM=BN=128, BK=32,
// 512 threads, triple-buffered 48KB LDS, distance-2, counted vmcnt(2),
// grid 768 = 3 blocks/CU, no tail.
// ---------------------------------------------------------------------------
__global__ __launch_bounds__(512, 6)
void gemm_qkv_kernel(const u16* __restrict__ A, const u16* __restrict__ B,
                     u16* __restrict__ Qo, u16* __restrict__ Ko, u16* __restrict__ Vt)
{
    __shared__ u16 Al[3][128 * 32];   // 3 x 8 KB
    __shared__ u16 Bl[3][128 * 32];   // 3 x 8 KB

    const int tid = threadIdx.x;
    const int l = tid & 63;
    const int w = tid >> 6;            // 0..7
    const int wm = w >> 2, wn = w & 3; // 2M x 4N
    const int lr = l & 15, lg = l >> 4;

    const int bid = blockIdx.x;                    // 0..767, 768%8==0
    const int swz = (bid & 7) * 96 + (bid >> 3);   // XCD-bijective
    const int mb = swz / 24, nbv = swz % 24;       // 32 x 24 blocks
    const int m0 = mb * 128, n0 = nbv * 128;

    const int arow = tid >> 2;                               // 0..127
    const int acol = ((tid & 3) ^ ((arow >> 1) & 3)) * 8;    // inv-swizzled col
    const int dstq = tid * 8;                                // u16 units
    const int rsw  = (lr >> 1) & 3;                          // read slot XOR

    f32x4 acc[4][2];
    #pragma unroll
    for (int i = 0; i < 4; ++i)
        #pragma unroll
        for (int j = 0; j < 2; ++j) acc[i][j] = (f32x4){0.f, 0.f, 0.f, 0.f};

    #pragma unroll
    for (int t = 0; t < 2; ++t) {
        const int k0 = t * 32;
        GLOAD16(A + (size_t)(m0 + arow) * D_MODEL + k0 + acol, &Al[t][dstq]);
        GLOAD16(B + (size_t)(n0 + arow) * D_MODEL + k0 + acol, &Bl[t][dstq]);
    }

    int cb = 0;                        // current buffer = t % 3
    for (int t = 0; t < 32; ++t) {
        if (t < 31) asm volatile("s_waitcnt vmcnt(2)" ::: "memory");
        else        asm volatile("s_waitcnt vmcnt(0)" ::: "memory");
        __builtin_amdgcn_s_barrier();

        if (t + 2 < 32) {
            const int sb = (cb >= 1) ? cb - 1 : cb + 2;   // (t+2)%3
            const int k0 = (t + 2) * 32;
            GLOAD16(A + (size_t)(m0 + arow) * D_MODEL + k0 + acol, &Al[sb][dstq]);
            GLOAD16(B + (size_t)(n0 + arow) * D_MODEL + k0 + acol, &Bl[sb][dstq]);
        }

        const u16* __restrict__ Ab = Al[cb];
        const u16* __restrict__ Bb = Bl[cb];
        bf16x8 af[4], bfr[2];
        #pragma unroll
        for (int i = 0; i < 4; ++i)
            af[i] = *reinterpret_cast<const bf16x8*>(
                &Ab[(wm * 64 + i * 16 + lr) * 32 + ((lg ^ rsw) * 8)]);
        #pragma unroll
        for (int j = 0; j < 2; ++j)
            bfr[j] = *reinterpret_cast<const bf16x8*>(
                &Bb[(wn * 32 + j * 16 + lr) * 32 + ((lg ^ rsw) * 8)]);

        __builtin_amdgcn_s_setprio(1);
        #pragma unroll
        for (int i = 0; i < 4; ++i)
            #pragma unroll
            for (int j = 0; j < 2; ++j)
                acc[i][j] = __builtin_amdgcn_mfma_f32_16x16x32_bf16(
                    af[i], bfr[j], acc[i][j], 0, 0, 0);
        __builtin_amdgcn_s_setprio(0);

        cb = (cb == 2) ? 0 : cb + 1;
    }

    const int z = (n0 >> 10);           // 0=Q 1=K 2=V (uniform per block)
    if (z < 2) {
        #pragma unroll
        for (int i = 0; i < 4; ++i) {
            #pragma unroll
            for (int r = 0; r < 4; ++r) {
                const int m = m0 + wm * 64 + i * 16 + lg * 4 + r;
                const int bb = m >> 11, s = m & (SEQ - 1);
                #pragma unroll
                for (int j = 0; j < 2; ++j) {
                    const int c = n0 + wn * 32 + j * 16 + lr;
                    const int cc = c & 1023, h = cc >> 6, d = cc & 63;
                    const size_t idx = ((size_t)(bb * NUM_HEADS + h) * SEQ + s) * 64 + d;
                    if (z == 0) Qo[idx] = f2bf(acc[i][j][r] * 0.18033688f);  // 1/8*log2e
                    else        Ko[idx] = f2bf(acc[i][j][r]);
                }
            }
        }
    } else {
        #pragma unroll
        for (int i = 0; i < 4; ++i) {
            const int mbase = m0 + wm * 64 + i * 16 + lg * 4;   // 4 consecutive s
            const int bb = mbase >> 11, s = mbase & (SEQ - 1);
            #pragma unroll
            for (int j = 0; j < 2; ++j) {
                const int c = n0 + wn * 32 + j * 16 + lr;
                const int cc = c & 1023, h = cc >> 6, d = cc & 63;
                u16 t4[4];
                #pragma unroll
                for (int r = 0; r < 4; ++r) t4[r] = f2bf(acc[i][j][r]);
                *reinterpret_cast<u64*>(
                    &Vt[((size_t)(bb * NUM_HEADS + h) * 64 + d) * SEQ + s]) =
                    *reinterpret_cast<u64*>(t4);
            }
        }
    }
}

// ---------------------------------------------------------------------------
// Output GEMM, pipelined, 8-wave (round-15, unchanged).
// ---------------------------------------------------------------------------
__global__ __launch_bounds__(512, 2)
void gemm_out_kernel(const u16* __restrict__ A, const u16* __restrict__ B,
                     const float* __restrict__ bias, float* __restrict__ out)
{
    __shared__ u16 Al[3][128 * 32];   // 3 x 8 KB
    __shared__ u16 Bl[3][128 * 32];   // 3 x 8 KB

    const int tid = threadIdx.x;
    const int l = tid & 63;
    const int w = tid >> 6;            // 0..7
    const int wm = w >> 2, wn = w & 3; // 2M x 4N
    const int lr = l & 15, lg = l >> 4;

    const int bid = blockIdx.x;                    // 0..255, 256%8==0
    const int swz = (bid & 7) * 32 + (bid >> 3);   // XCD-bijective
    const int mb = swz >> 3, nb = swz & 7;         // 32 x 8 blocks
    const int m0 = mb * 128, n0 = nb * 128;

    const int arow = tid >> 2;                               // 0..127
    const int acol = ((tid & 3) ^ ((arow >> 1) & 3)) * 8;
    const int dstq = tid * 8;                                // u16 units
    const int rsw  = (lr >> 1) & 3;

    f32x4 acc[4][2];
    #pragma unroll
    for (int i = 0; i < 4; ++i)
        #pragma unroll
        for (int j = 0; j < 2; ++j) acc[i][j] = (f32x4){0.f, 0.f, 0.f, 0.f};

    #pragma unroll
    for (int t = 0; t < 2; ++t) {
        const int k0 = t * 32;
        GLOAD16(A + (size_t)(m0 + arow) * D_MODEL + k0 + acol, &Al[t][dstq]);
        GLOAD16(B + (size_t)(n0 + arow) * D_MODEL + k0 + acol, &Bl[t][dstq]);
    }

    int cb = 0;
    for (int t = 0; t < 32; ++t) {
        if (t < 31) asm volatile("s_waitcnt vmcnt(2)" ::: "memory");
        else        asm volatile("s_waitcnt vmcnt(0)" ::: "memory");
        __builtin_amdgcn_s_barrier();

        if (t + 2 < 32) {
            const int sb = (cb >= 1) ? cb - 1 : cb + 2;   // (t+2)%3
            const int k0 = (t + 2) * 32;
            GLOAD16(A + (size_t)(m0 + arow) * D_MODEL + k0 + acol, &Al[sb][dstq]);
            GLOAD16(B + (size_t)(n0 + arow) * D_MODEL + k0 + acol, &Bl[sb][dstq]);
        }

        const u16* __restrict__ Ab = Al[cb];
        const u16* __restrict__ Bb = Bl[cb];
        bf16x8 af[4], bfr[2];
        #pragma unroll
        for (int i = 0; i < 4; ++i)
            af[i] = *reinterpret_cast<const bf16x8*>(
                &Ab[(wm * 64 + i * 16 + lr) * 32 + ((lg ^ rsw) * 8)]);
        #pragma unroll
        for (int j = 0; j < 2; ++j)
            bfr[j] = *reinterpret_cast<const bf16x8*>(
                &Bb[(wn * 32 + j * 16 + lr) * 32 + ((lg ^ rsw) * 8)]);

        __builtin_amdgcn_s_setprio(1);
        #pragma unroll
        for (int i = 0; i < 4; ++i)
            #pragma unroll
            for (int j = 0; j < 2; ++j)
                acc[i][j] = __builtin_amdgcn_mfma_f32_16x16x32_bf16(
                    af[i], bfr[j], acc[i][j], 0, 0, 0);
        __builtin_amdgcn_s_setprio(0);

        cb = (cb == 2) ? 0 : cb + 1;
    }

    #pragma unroll
    for (int i = 0; i < 4; ++i) {
        #pragma unroll
        for (int r = 0; r < 4; ++r) {
            const int m = m0 + wm * 64 + i * 16 + lg * 4 + r;
            #pragma unroll
            for (int j = 0; j < 2; ++j) {
                const int c = n0 + wn * 32 + j * 16 + lr;
                out[(size_t)m * D_MODEL + c] = acc[i][j][r] + bias[c];
            }
        }
    }
}

// ---------------------------------------------------------------------------
// Split-S MFMA causal flash attention, QBLK=128, T15 carried-S pipeline:
// S(it+1) MFMA (independent) overlaps softmax(s_carry) VALU; PV(it) after.
// Triple-buffered 48KB LDS. Per iter: vmcnt(0) -> barrier -> DMA(it+2) ->
// S_next || softmax -> PV -> carry. WAR: buf (it+2)%3's readers (K in it-2,
// V in it-1) precede this iter's barrier.
// ---------------------------------------------------------------------------
__device__ __forceinline__ void map_pair128(int p, int& qt2, int& ch) {
    if (p < 16)      { qt2 = 15 - (p >> 2); ch = p & 3; }
    else if (p < 28) { int t = p - 16; qt2 = 11 - t / 3; ch = t % 3; }
    else if (p < 36) { int t = p - 28; qt2 = 7 - (t >> 1); ch = t & 1; }
    else             { qt2 = 39 - p; ch = 0; }
}

__global__ __launch_bounds__(256)
void attn_kernel(const u16* __restrict__ Q, const u16* __restrict__ K,
                 const u16* __restrict__ Vt, u16* __restrict__ ctx,
                 u16* __restrict__ Opart, float* __restrict__ Lpart)
{
    __shared__ char LdsB[3][16384];   // per buf: K 8KB @0, V 8KB @8192

    const int tid = threadIdx.x;
    const int l = tid & 63;
    const int w = tid >> 6;
    const int lr = l & 15;
    const int lg = l >> 4;

    const int xcd  = blockIdx.x & 7;
    const int slot = blockIdx.x >> 3;          // 0..159
    const int bh   = xcd * 4 + slot / 40;      // 4 heads per XCD chunk
    int qt2, ch;
    map_pair128(slot % 40, qt2, ch);

    const int ntiles = 2 * qt2 + 2;
    const int nch  = (ntiles + 7) >> 3;        // ceil(ntiles/8)
    const int base = ntiles / nch, rem = ntiles % nch;
    const int start = ch * base + (ch < rem ? ch : rem);
    const int cnt   = base + (ch < rem ? 1 : 0);

    const size_t hbase = (size_t)bh * SEQ * 64;
    const int b = bh >> 4, h = bh & (NUM_HEADS - 1);
    const u16* __restrict__ Kh = K + hbase;
    const u16* __restrict__ Vh = Vt + hbase;
    const int q0 = qt2 * 128;

    const int r0 = tid >> 3;
    const int c0 = ((tid & 7) ^ (r0 & 7)) * 8;
    const int r1 = (256 + tid) >> 3;
    const int c1 = ((tid & 7) ^ (r1 & 7)) * 8;
    const int d0b = tid * 16;
    const int d1b = 4096 + tid * 16;
    const int rswz = (lr & 7) << 4;

    bf16x8 qf[2][2];
    #pragma unroll
    for (int fq = 0; fq < 2; ++fq) {
        const u16* qp = Q + hbase + (size_t)(q0 + fq * 64 + w * 16 + lr) * 64 + lg * 8;
        qf[fq][0] = *reinterpret_cast<const bf16x8*>(qp);
        qf[fq][1] = *reinterpret_cast<const bf16x8*>(qp + 32);
    }
    asm volatile("s_waitcnt vmcnt(0)" ::: "memory");   // keep stage-FIFO math exact

    f32x4 acc[2][4];
    #pragma unroll
    for (int fq = 0; fq < 2; ++fq)
        #pragma unroll
        for (int nb = 0; nb < 4; ++nb) acc[fq][nb] = (f32x4){0.f, 0.f, 0.f, 0.f};
    float lsumv[2] = {0.f, 0.f};

    // prologue: stage start (buf0) and start+1 (buf1)
    {
        const int kb64 = start * 64;
        GLOAD16(Kh + (size_t)(kb64 + r0) * 64 + c0, LdsB[0] + d0b);
        GLOAD16(Kh + (size_t)(kb64 + r1) * 64 + c1, LdsB[0] + d1b);
        GLOAD16(Vh + (size_t)r0 * SEQ + kb64 + c0, LdsB[0] + 8192 + d0b);
        GLOAD16(Vh + (size_t)r1 * SEQ + kb64 + c1, LdsB[0] + 8192 + d1b);
    }
    if (cnt > 1) {
        const int kb64 = (start + 1) * 64;
        GLOAD16(Kh + (size_t)(kb64 + r0) * 64 + c0, LdsB[1] + d0b);
        GLOAD16(Kh + (size_t)(kb64 + r1) * 64 + c1, LdsB[1] + d1b);
        GLOAD16(Vh + (size_t)r0 * SEQ + kb64 + c0, LdsB[1] + 8192 + d0b);
        GLOAD16(Vh + (size_t)r1 * SEQ + kb64 + c1, LdsB[1] + 8192 + d1b);
        asm volatile("s_waitcnt vmcnt(4)" ::: "memory");   // tile start resident
    } else {
        asm volatile("s_waitcnt vmcnt(0)" ::: "memory");
    }
    __builtin_amdgcn_s_barrier();      // publish buf0

    // S(start) into the carry registers
    f32x4 scur[2][4];
    {
        const char* kbuf = LdsB[0];
        bf16x8 kf[4][2];
        #pragma unroll
        for (int m = 0; m < 4; ++m) {
            const char* krow = kbuf + (16 * m + lr) * 128;
            kf[m][0] = *reinterpret_cast<const bf16x8*>(krow + ((lg * 16) ^ rswz));
            kf[m][1] = *reinterpret_cast<const bf16x8*>(krow + ((64 + lg * 16) ^ rswz));
        }
        #pragma unroll
        for (int fq = 0; fq < 2; ++fq)
            #pragma unroll
            for (int m = 0; m < 4; ++m) {
                scur[fq][m] = (f32x4){0.f, 0.f, 0.f, 0.f};
                scur[fq][m] = __builtin_amdgcn_mfma_f32_16x16x32_bf16(
                    kf[m][0], qf[fq][0], scur[fq][m], 0, 0, 0);
                scur[fq][m] = __builtin_amdgcn_mfma_f32_16x16x32_bf16(
                    kf[m][1], qf[fq][1], scur[fq][m], 0, 0, 0);
            }
    }

    int cb = 0;                                  // buffer holding tile `it`
    for (int it = 0; it < cnt; ++it) {
        const int tile = start + it;

        asm volatile("s_waitcnt vmcnt(0)" ::: "memory");   // tile it+1 resident
        __builtin_amdgcn_s_barrier();            // publish + close old readers

        if (it + 2 < cnt) {                      // issue tile it+2 -> (it+2)%3
            const int sb = (cb >= 1) ? cb - 1 : cb + 2;
            const int kb64 = (tile + 2) * 64;
            GLOAD16(Kh + (size_t)(kb64 + r0) * 64 + c0, LdsB[sb] + d0b);
            GLOAD16(Kh + (size_t)(kb64 + r1) * 64 + c1, LdsB[sb] + d1b);
            GLOAD16(Vh + (size_t)r0 * SEQ + kb64 + c0, LdsB[sb] + 8192 + d0b);
            GLOAD16(Vh + (size_t)r1 * SEQ + kb64 + c1, LdsB[sb] + 8192 + d1b);
        }

        // --- S(it+1): independent MFMA, overlaps softmax VALU below ---
        f32x4 snx[2][4];
        const bool have_next = (it + 1 < cnt);
        if (have_next) {
            const char* kbuf = LdsB[(cb == 2) ? 0 : cb + 1];
            bf16x8 kf[4][2];
            #pragma unroll
            for (int m = 0; m < 4; ++m) {
                const char* krow = kbuf + (16 * m + lr) * 128;
                kf[m][0] = *reinterpret_cast<const bf16x8*>(krow + ((lg * 16) ^ rswz));
                kf[m][1] = *reinterpret_cast<const bf16x8*>(krow + ((64 + lg * 16) ^ rswz));
            }
            #pragma unroll
            for (int fq = 0; fq < 2; ++fq)
                #pragma unroll
                for (int m = 0; m < 4; ++m) {
                    snx[fq][m] = (f32x4){0.f, 0.f, 0.f, 0.f};
                    snx[fq][m] = __builtin_amdgcn_mfma_f32_16x16x32_bf16(
                        kf[m][0], qf[fq][0], snx[fq][m], 0, 0, 0);
                    snx[fq][m] = __builtin_amdgcn_mfma_f32_16x16x32_bf16(
                        kf[m][1], qf[fq][1], snx[fq][m], 0, 0, 0);
                }
        }

        // --- softmax on carried S (VALU; overlaps S_next MFMA) ---
        const bool diag = (tile >= 2 * qt2);
        const int koff0 = (tile - 2 * qt2) * 64;
        unsigned dw[2][4][2];
        #pragma unroll
        for (int fq = 0; fq < 2; ++fq) {
            if (diag) {
                const int qloc = fq * 64 + w * 16 + lr;
                #pragma unroll
                for (int m = 0; m < 4; ++m)
                    #pragma unroll
                    for (int r = 0; r < 4; ++r)
                        if (koff0 + 16 * m + 4 * lg + r > qloc) scur[fq][m][r] = -1.0e38f;
            }
            float p[4][4];
            #pragma unroll
            for (int m = 0; m < 4; ++m) {
                #pragma unroll
                for (int r = 0; r < 4; ++r) p[m][r] = EXP2(scur[fq][m][r]);
                lsumv[fq] += (p[m][0] + p[m][1]) + (p[m][2] + p[m][3]);
                dw[fq][m][0] = cvt_pk_bf16(p[m][0], p[m][1]);
                dw[fq][m][1] = cvt_pk_bf16(p[m][2], p[m][3]);
            }
        }

        // --- PV(it) ---
        const char* vbuf = LdsB[cb] + 8192;
        __builtin_amdgcn_s_setprio(1);
        #pragma unroll
        for (int c = 0; c < 2; ++c) {
            union Pu { unsigned u[4]; bf16x8 v; } pb[2];
            #pragma unroll
            for (int fq = 0; fq < 2; ++fq) {
                pb[fq].u[0] = dw[fq][2 * c][0];     pb[fq].u[1] = dw[fq][2 * c][1];
                pb[fq].u[2] = dw[fq][2 * c + 1][0]; pb[fq].u[3] = dw[fq][2 * c + 1][1];
            }
            #pragma unroll
            for (int nb = 0; nb < 4; ++nb) {
                const char* vrow = vbuf + (16 * nb + lr) * 128;
                union Vu { s16x4 hv[2]; bf16x8 v; } vf;
                vf.hv[0] = *reinterpret_cast<const s16x4*>(
                    vrow + ((c * 64 + lg * 8) ^ rswz));
                vf.hv[1] = *reinterpret_cast<const s16x4*>(
                    vrow + ((c * 64 + 32 + lg * 8) ^ rswz));
                acc[0][nb] = __builtin_amdgcn_mfma_f32_16x16x32_bf16(
                    vf.v, pb[0].v, acc[0][nb], 0, 0, 0);
                acc[1][nb] = __builtin_amdgcn_mfma_f32_16x16x32_bf16(
                    vf.v, pb[1].v, acc[1][nb], 0, 0, 0);
            }
        }
        __builtin_amdgcn_s_setprio(0);

        if (have_next) {                         // carry
            #pragma unroll
            for (int fq = 0; fq < 2; ++fq)
                #pragma unroll
                for (int m = 0; m < 4; ++m) scur[fq][m] = snx[fq][m];
        }
        cb = (cb == 2) ? 0 : cb + 1;
    }

    #pragma unroll
    for (int fq = 0; fq < 2; ++fq) {
        lsumv[fq] += __shfl_xor(lsumv[fq], 16);
        lsumv[fq] += __shfl_xor(lsumv[fq], 32);
    }

    if (nch == 1) {
        #pragma unroll
        for (int fq = 0; fq < 2; ++fq) {
            const float inv = 1.0f / lsumv[fq];
            const int qrow = q0 + fq * 64 + w * 16 + lr;
            u16* op = ctx + ((size_t)(b * SEQ) + qrow) * D_MODEL + h * 64 + 4 * lg;
            #pragma unroll
            for (int nb = 0; nb < 4; ++nb) {
                u16 t4[4];
                #pragma unroll
                for (int r = 0; r < 4; ++r) t4[r] = f2bf(acc[fq][nb][r] * inv);
                *reinterpret_cast<u64*>(op + 16 * nb) = *reinterpret_cast<u64*>(t4);
            }
        }
    } else {
        const int slot4 = ((bh * 12 + (qt2 - 4)) << 2) + ch;
        #pragma unroll
        for (int fq = 0; fq < 2; ++fq) {
            const int rloc = fq * 64 + w * 16 + lr;
            u16* op = Opart + (size_t)slot4 * 8192 + rloc * 64 + 4 * lg;
            #pragma unroll
            for (int nb = 0; nb < 4; ++nb) {
                u16 t4[4];
                #pragma unroll
                for (int r = 0; r < 4; ++r) t4[r] = f2bf(acc[fq][nb][r]);
                *reinterpret_cast<u64*>(op + 16 * nb) = *reinterpret_cast<u64*>(t4);
            }
            if (lg == 0) Lpart[slot4 * 128 + rloc] = lsumv[fq];
        }
    }
}

// Sum partials (<=4) for each (bh, qt2>=4), normalize, write ctx.
__global__ __launch_bounds__(128)
void attn_reduce_kernel(const u16* __restrict__ Opart,
                        const float* __restrict__ Lpart,
                        u16* __restrict__ ctx)
{
    const int blk = blockIdx.x;          // 0..383
    const int bh = blk / 12, idx = blk % 12;
    const int qt2 = idx + 4;
    const int nch = (2 * qt2 + 2 + 7) >> 3;
    const int t = threadIdx.x;           // query row in 128-tile
    const int b = bh >> 4, h = bh & (NUM_HEADS - 1);
    const int slot0 = (bh * 12 + idx) << 2;

    float acc[64] = {};
    float lt = 0.f;
    for (int ch = 0; ch < nch; ++ch) {
        const u16* op = Opart + (size_t)(slot0 + ch) * 8192 + t * 64;
        lt += Lpart[(slot0 + ch) * 128 + t];
        #pragma unroll
        for (int cchunk = 0; cchunk < 8; ++cchunk) {
            u16 v[8];
            *reinterpret_cast<int4*>(v) =
                *reinterpret_cast<const int4*>(op + cchunk * 8);
            #pragma unroll
            for (int j = 0; j < 8; ++j) acc[cchunk * 8 + j] += bf2f(v[j]);
        }
    }
    const float inv = 1.0f / lt;
    u16* orow = ctx + ((size_t)(b * SEQ) + qt2 * 128 + t) * D_MODEL + h * 64;
    #pragma unroll
    for (int cchunk = 0; cchunk < 8; ++cchunk) {
        u16 v[8];
        #pragma unroll
        for (int j = 0; j < 8; ++j) v[j] = f2bf(acc[cchunk * 8 + j] * inv);
        *reinterpret_cast<int4*>(orow + cchunk * 8) = *reinterpret_cast<int4*>(v);
    }
}

// ---------------------------------------------------------------------------

extern "C" void kernel_launch(void* const* d_in, const int* in_sizes, int n_in,
                              void* d_out, int out_size, void* d_ws, size_t ws_size,
                              hipStream_t stream)
{
    const float* x  = (const float*)d_in[0];
    const float* Wq = (const float*)d_in[1];
    const float* Wk = (const float*)d_in[2];
    const float* Wv = (const float*)d_in[3];
    const float* Wo = (const float*)d_in[4];
    const float* bo = (const float*)d_in[5];
    float* out = (float*)d_out;

    u16* xb   = (u16*)d_ws;                               // 4096*1024
    u16* wqkv = xb   + (size_t)MTOT * D_MODEL;            // 3072*1024
    u16* wob  = wqkv + (size_t)3 * D_MODEL * D_MODEL;     // 1024*1024
    u16* Qw   = wob  + (size_t)D_MODEL * D_MODEL;         // [b,h,s,d] (pre-scaled)
    u16* Kw   = Qw   + (size_t)MTOT * D_MODEL;            // [b,h,s,d]
    u16* Vtw  = Kw   + (size_t)MTOT * D_MODEL;            // [b,h,d,s]
    u16* ctxb = Vtw  + (size_t)MTOT * D_MODEL;            // [4096][1024]
    u16* Opart = ctxb + (size_t)MTOT * D_MODEL;           // 1536 slots x 8192
    float* Lpart = (float*)(Opart + (size_t)1536 * 8192); // 1536 x 128

    cast_all_kernel<<<4096, 256, 0, stream>>>(x, Wq, Wk, Wv, Wo, xb);

    gemm_qkv_kernel<<<dim3(768), 512, 0, stream>>>(xb, wqkv, Qw, Kw, Vtw);

    attn_kernel<<<dim3(1280), 256, 0, stream>>>(Qw, Kw, Vtw, ctxb, Opart, Lpart);
    attn_reduce_kernel<<<dim3(384), 128, 0, stream>>>(Opart, Lpart, ctxb);

    gemm_out_kernel<<<dim3(256), 512, 0, stream>>>(ctxb, wob, bo, out);
}

// Round 19
// 111.449 us; speedup vs baseline: 1.0305x; 1.0305x over previous
//
#include <hip/hip_runtime.h>

#define D_MODEL 1024
#define NUM_HEADS 16
#define HEAD_DIM 64
#define BATCH 2
#define SEQ 2048
#define MTOT (BATCH * SEQ)   // 4096

typedef __attribute__((ext_vector_type(8))) short bf16x8;   // 8 bf16 in 4 VGPRs
typedef __attribute__((ext_vector_type(4))) short s16x4;
typedef __attribute__((ext_vector_type(4))) float f32x4;
typedef unsigned short u16;
typedef unsigned long long u64;

__device__ __forceinline__ u16 f2bf(float f) {
    unsigned u = __float_as_uint(f);
    return (u16)((u + 0x7FFFu + ((u >> 16) & 1u)) >> 16);   // RNE, finite data
}
__device__ __forceinline__ float bf2f(u16 v) {
    return __uint_as_float((unsigned)v << 16);
}

__device__ __forceinline__ unsigned cvt_pk_bf16(float lo, float hi) {
    unsigned r;
    asm volatile("v_cvt_pk_bf16_f32 %0, %1, %2" : "=v"(r) : "v"(lo), "v"(hi));
    return r;
}

#if __has_builtin(__builtin_amdgcn_exp2f)
#define EXP2(x) __builtin_amdgcn_exp2f(x)
#else
#define EXP2(x) exp2f(x)
#endif

#define GLOAD16(gp, lp) __builtin_amdgcn_global_load_lds(                      \
    (const __attribute__((address_space(1))) void*)(gp),                       \
    (__attribute__((address_space(3))) void*)(lp), 16, 0, 0)

// ---------------------------------------------------------------------------
// One merged fp32 -> bf16 cast: x | Wqkv | Wo into contiguous ws region.
// ---------------------------------------------------------------------------
__global__ __launch_bounds__(256)
void cast_all_kernel(const float* __restrict__ x,  const float* __restrict__ Wq,
                     const float* __restrict__ Wk, const float* __restrict__ Wv,
                     const float* __restrict__ Wo, u16* __restrict__ dst)
{
    const int i = blockIdx.x * 256 + threadIdx.x;   // 1048576 groups of 8
    const float* src;
    int j;
    if (i < 524288) { src = x; j = i; }
    else if (i < 917504) {
        const int k = i - 524288;
        const int z = k >> 17;
        src = (z == 0) ? Wq : (z == 1) ? Wk : Wv;
        j = k & 0x1FFFF;
    } else { src = Wo; j = i - 917504; }
    const float4* s = reinterpret_cast<const float4*>(src) + (size_t)j * 2;
    float4 a = s[0], b = s[1];
    u16 tmp[8] = {f2bf(a.x), f2bf(a.y), f2bf(a.z), f2bf(a.w),
                  f2bf(b.x), f2bf(b.y), f2bf(b.z), f2bf(b.w)};
    *reinterpret_cast<int4*>(dst + (size_t)i * 8) = *reinterpret_cast<int4*>(tmp);
}

// ---------------------------------------------------------------------------
// QKV GEMM, pipelined, 8-wave: BM=BN=128, BK=32, 512 threads (2Mx4N,
// 64x32/wave), triple-buffered 48KB LDS, distance-2, counted vmcnt(2),
// grid 768 = 3 blocks/CU, no tail. Epilogue: Q pre-scaled 0.125*log2e,
// K [b,h,s,d], V^T [b,h,d,s].
// ---------------------------------------------------------------------------
__global__ __launch_bounds__(512, 6)
void gemm_qkv_kernel(const u16* __restrict__ A, const u16* __restrict__ B,
                     u16* __restrict__ Qo, u16* __restrict__ Ko, u16* __restrict__ Vt)
{
    __shared__ u16 Al[3][128 * 32];   // 3 x 8 KB
    __shared__ u16 Bl[3][128 * 32];   // 3 x 8 KB

    const int tid = threadIdx.x;
    const int l = tid & 63;
    const int w = tid >> 6;            // 0..7
    const int wm = w >> 2, wn = w & 3; // 2M x 4N
    const int lr = l & 15, lg = l >> 4;

    const int bid = blockIdx.x;                    // 0..767, 768%8==0
    const int swz = (bid & 7) * 96 + (bid >> 3);   // XCD-bijective
    const int mb = swz / 24, nbv = swz % 24;       // 32 x 24 blocks
    const int m0 = mb * 128, n0 = nbv * 128;

    const int arow = tid >> 2;                               // 0..127
    const int acol = ((tid & 3) ^ ((arow >> 1) & 3)) * 8;    // inv-swizzled col
    const int dstq = tid * 8;                                // u16 units
    const int rsw  = (lr >> 1) & 3;                          // read slot XOR

    f32x4 acc[4][2];
    #pragma unroll
    for (int i = 0; i < 4; ++i)
        #pragma unroll
        for (int j = 0; j < 2; ++j) acc[i][j] = (f32x4){0.f, 0.f, 0.f, 0.f};

    #pragma unroll
    for (int t = 0; t < 2; ++t) {
        const int k0 = t * 32;
        GLOAD16(A + (size_t)(m0 + arow) * D_MODEL + k0 + acol, &Al[t][dstq]);
        GLOAD16(B + (size_t)(n0 + arow) * D_MODEL + k0 + acol, &Bl[t][dstq]);
    }

    int cb = 0;                        // current buffer = t % 3
    for (int t = 0; t < 32; ++t) {
        if (t < 31) asm volatile("s_waitcnt vmcnt(2)" ::: "memory");
        else        asm volatile("s_waitcnt vmcnt(0)" ::: "memory");
        __builtin_amdgcn_s_barrier();

        if (t + 2 < 32) {
            const int sb = (cb >= 1) ? cb - 1 : cb + 2;   // (t+2)%3
            const int k0 = (t + 2) * 32;
            GLOAD16(A + (size_t)(m0 + arow) * D_MODEL + k0 + acol, &Al[sb][dstq]);
            GLOAD16(B + (size_t)(n0 + arow) * D_MODEL + k0 + acol, &Bl[sb][dstq]);
        }

        const u16* __restrict__ Ab = Al[cb];
        const u16* __restrict__ Bb = Bl[cb];
        bf16x8 af[4], bfr[2];
        #pragma unroll
        for (int i = 0; i < 4; ++i)
            af[i] = *reinterpret_cast<const bf16x8*>(
                &Ab[(wm * 64 + i * 16 + lr) * 32 + ((lg ^ rsw) * 8)]);
        #pragma unroll
        for (int j = 0; j < 2; ++j)
            bfr[j] = *reinterpret_cast<const bf16x8*>(
                &Bb[(wn * 32 + j * 16 + lr) * 32 + ((lg ^ rsw) * 8)]);

        __builtin_amdgcn_s_setprio(1);
        #pragma unroll
        for (int i = 0; i < 4; ++i)
            #pragma unroll
            for (int j = 0; j < 2; ++j)
                acc[i][j] = __builtin_amdgcn_mfma_f32_16x16x32_bf16(
                    af[i], bfr[j], acc[i][j], 0, 0, 0);
        __builtin_amdgcn_s_setprio(0);

        cb = (cb == 2) ? 0 : cb + 1;
    }

    const int z = (n0 >> 10);           // 0=Q 1=K 2=V (uniform per block)
    if (z < 2) {
        #pragma unroll
        for (int i = 0; i < 4; ++i) {
            #pragma unroll
            for (int r = 0; r < 4; ++r) {
                const int m = m0 + wm * 64 + i * 16 + lg * 4 + r;
                const int bb = m >> 11, s = m & (SEQ - 1);
                #pragma unroll
                for (int j = 0; j < 2; ++j) {
                    const int c = n0 + wn * 32 + j * 16 + lr;
                    const int cc = c & 1023, h = cc >> 6, d = cc & 63;
                    const size_t idx = ((size_t)(bb * NUM_HEADS + h) * SEQ + s) * 64 + d;
                    if (z == 0) Qo[idx] = f2bf(acc[i][j][r] * 0.18033688f);  // 1/8*log2e
                    else        Ko[idx] = f2bf(acc[i][j][r]);
                }
            }
        }
    } else {
        #pragma unroll
        for (int i = 0; i < 4; ++i) {
            const int mbase = m0 + wm * 64 + i * 16 + lg * 4;   // 4 consecutive s
            const int bb = mbase >> 11, s = mbase & (SEQ - 1);
            #pragma unroll
            for (int j = 0; j < 2; ++j) {
                const int c = n0 + wn * 32 + j * 16 + lr;
                const int cc = c & 1023, h = cc >> 6, d = cc & 63;
                u16 t4[4];
                #pragma unroll
                for (int r = 0; r < 4; ++r) t4[r] = f2bf(acc[i][j][r]);
                *reinterpret_cast<u64*>(
                    &Vt[((size_t)(bb * NUM_HEADS + h) * 64 + d) * SEQ + s]) =
                    *reinterpret_cast<u64*>(t4);
            }
        }
    }
}

// ---------------------------------------------------------------------------
// Output GEMM, pipelined, 8-wave: ctx[4096][1024] @ Wo^T + bo, fp32 out.
// Same template (512 thr, 2Mx4N, vmcnt(2), 48KB 3-buf). Grid 256 = 1/CU.
// ---------------------------------------------------------------------------
__global__ __launch_bounds__(512, 2)
void gemm_out_kernel(const u16* __restrict__ A, const u16* __restrict__ B,
                     const float* __restrict__ bias, float* __restrict__ out)
{
    __shared__ u16 Al[3][128 * 32];   // 3 x 8 KB
    __shared__ u16 Bl[3][128 * 32];   // 3 x 8 KB

    const int tid = threadIdx.x;
    const int l = tid & 63;
    const int w = tid >> 6;            // 0..7
    const int wm = w >> 2, wn = w & 3; // 2M x 4N
    const int lr = l & 15, lg = l >> 4;

    const int bid = blockIdx.x;                    // 0..255, 256%8==0
    const int swz = (bid & 7) * 32 + (bid >> 3);   // XCD-bijective
    const int mb = swz >> 3, nb = swz & 7;         // 32 x 8 blocks
    const int m0 = mb * 128, n0 = nb * 128;

    const int arow = tid >> 2;                               // 0..127
    const int acol = ((tid & 3) ^ ((arow >> 1) & 3)) * 8;
    const int dstq = tid * 8;                                // u16 units
    const int rsw  = (lr >> 1) & 3;

    f32x4 acc[4][2];
    #pragma unroll
    for (int i = 0; i < 4; ++i)
        #pragma unroll
        for (int j = 0; j < 2; ++j) acc[i][j] = (f32x4){0.f, 0.f, 0.f, 0.f};

    #pragma unroll
    for (int t = 0; t < 2; ++t) {
        const int k0 = t * 32;
        GLOAD16(A + (size_t)(m0 + arow) * D_MODEL + k0 + acol, &Al[t][dstq]);
        GLOAD16(B + (size_t)(n0 + arow) * D_MODEL + k0 + acol, &Bl[t][dstq]);
    }

    int cb = 0;
    for (int t = 0; t < 32; ++t) {
        if (t < 31) asm volatile("s_waitcnt vmcnt(2)" ::: "memory");
        else        asm volatile("s_waitcnt vmcnt(0)" ::: "memory");
        __builtin_amdgcn_s_barrier();

        if (t + 2 < 32) {
            const int sb = (cb >= 1) ? cb - 1 : cb + 2;   // (t+2)%3
            const int k0 = (t + 2) * 32;
            GLOAD16(A + (size_t)(m0 + arow) * D_MODEL + k0 + acol, &Al[sb][dstq]);
            GLOAD16(B + (size_t)(n0 + arow) * D_MODEL + k0 + acol, &Bl[sb][dstq]);
        }

        const u16* __restrict__ Ab = Al[cb];
        const u16* __restrict__ Bb = Bl[cb];
        bf16x8 af[4], bfr[2];
        #pragma unroll
        for (int i = 0; i < 4; ++i)
            af[i] = *reinterpret_cast<const bf16x8*>(
                &Ab[(wm * 64 + i * 16 + lr) * 32 + ((lg ^ rsw) * 8)]);
        #pragma unroll
        for (int j = 0; j < 2; ++j)
            bfr[j] = *reinterpret_cast<const bf16x8*>(
                &Bb[(wn * 32 + j * 16 + lr) * 32 + ((lg ^ rsw) * 8)]);

        __builtin_amdgcn_s_setprio(1);
        #pragma unroll
        for (int i = 0; i < 4; ++i)
            #pragma unroll
            for (int j = 0; j < 2; ++j)
                acc[i][j] = __builtin_amdgcn_mfma_f32_16x16x32_bf16(
                    af[i], bfr[j], acc[i][j], 0, 0, 0);
        __builtin_amdgcn_s_setprio(0);

        cb = (cb == 2) ? 0 : cb + 1;
    }

    #pragma unroll
    for (int i = 0; i < 4; ++i) {
        #pragma unroll
        for (int r = 0; r < 4; ++r) {
            const int m = m0 + wm * 64 + i * 16 + lg * 4 + r;
            #pragma unroll
            for (int j = 0; j < 2; ++j) {
                const int c = n0 + wn * 32 + j * 16 + lr;
                out[(size_t)m * D_MODEL + c] = acc[i][j][r] + bias[c];
            }
        }
    }
}

// ---------------------------------------------------------------------------
// Split-S MFMA causal flash attention, QBLK=128 (best measured version).
// One barrier/tile, double-buffered 32KB LDS, split-S linear partials.
// ---------------------------------------------------------------------------
__device__ __forceinline__ void map_pair128(int p, int& qt2, int& ch) {
    if (p < 16)      { qt2 = 15 - (p >> 2); ch = p & 3; }
    else if (p < 28) { int t = p - 16; qt2 = 11 - t / 3; ch = t % 3; }
    else if (p < 36) { int t = p - 28; qt2 = 7 - (t >> 1); ch = t & 1; }
    else             { qt2 = 39 - p; ch = 0; }
}

__global__ __launch_bounds__(256)
void attn_kernel(const u16* __restrict__ Q, const u16* __restrict__ K,
                 const u16* __restrict__ Vt, u16* __restrict__ ctx,
                 u16* __restrict__ Opart, float* __restrict__ Lpart)
{
    __shared__ char LdsB[2][16384];   // per buf: K 8KB @0, V 8KB @8192

    const int tid = threadIdx.x;
    const int l = tid & 63;
    const int w = tid >> 6;
    const int lr = l & 15;
    const int lg = l >> 4;

    const int xcd  = blockIdx.x & 7;
    const int slot = blockIdx.x >> 3;          // 0..159
    const int bh   = xcd * 4 + slot / 40;      // 4 heads per XCD chunk
    int qt2, ch;
    map_pair128(slot % 40, qt2, ch);

    const int ntiles = 2 * qt2 + 2;
    const int nch  = (ntiles + 7) >> 3;        // ceil(ntiles/8)
    const int base = ntiles / nch, rem = ntiles % nch;
    const int start = ch * base + (ch < rem ? ch : rem);
    const int cnt   = base + (ch < rem ? 1 : 0);

    const size_t hbase = (size_t)bh * SEQ * 64;
    const int b = bh >> 4, h = bh & (NUM_HEADS - 1);
    const u16* __restrict__ Kh = K + hbase;
    const u16* __restrict__ Vh = Vt + hbase;
    const int q0 = qt2 * 128;

    const int r0 = tid >> 3;
    const int c0 = ((tid & 7) ^ (r0 & 7)) * 8;
    const int r1 = (256 + tid) >> 3;
    const int c1 = ((tid & 7) ^ (r1 & 7)) * 8;
    const int d0b = tid * 16;
    const int d1b = 4096 + tid * 16;
    const int rswz = (lr & 7) << 4;

    bf16x8 qf[2][2];
    #pragma unroll
    for (int fq = 0; fq < 2; ++fq) {
        const u16* qp = Q + hbase + (size_t)(q0 + fq * 64 + w * 16 + lr) * 64 + lg * 8;
        qf[fq][0] = *reinterpret_cast<const bf16x8*>(qp);
        qf[fq][1] = *reinterpret_cast<const bf16x8*>(qp + 32);
    }
    asm volatile("s_waitcnt vmcnt(0)" ::: "memory");   // keep stage-FIFO math exact

    f32x4 acc[2][4];
    #pragma unroll
    for (int fq = 0; fq < 2; ++fq)
        #pragma unroll
        for (int nb = 0; nb < 4; ++nb) acc[fq][nb] = (f32x4){0.f, 0.f, 0.f, 0.f};
    float lsumv[2] = {0.f, 0.f};

    {   // prologue: stage tile `start` -> buf 0 (4 loads in flight)
        char* kb = LdsB[0];
        char* vb = LdsB[0] + 8192;
        const int kb64 = start * 64;
        GLOAD16(Kh + (size_t)(kb64 + r0) * 64 + c0, kb + d0b);
        GLOAD16(Kh + (size_t)(kb64 + r1) * 64 + c1, kb + d1b);
        GLOAD16(Vh + (size_t)r0 * SEQ + kb64 + c0, vb + d0b);
        GLOAD16(Vh + (size_t)r1 * SEQ + kb64 + c1, vb + d1b);
    }

    for (int it = 0; it < cnt; ++it) {
        const int tile = start + it;
        const int buf = it & 1;

        // single per-tile checkpoint: tile `it` ready, publish to all waves
        asm volatile("s_waitcnt vmcnt(0)" ::: "memory");
        __builtin_amdgcn_s_barrier();

        if (it < cnt - 1) {                      // issue next tile's DMA now
            const int kb64 = (tile + 1) * 64;
            char* kbl = LdsB[buf ^ 1];
            char* vbl = kbl + 8192;
            GLOAD16(Kh + (size_t)(kb64 + r0) * 64 + c0, kbl + d0b);
            GLOAD16(Kh + (size_t)(kb64 + r1) * 64 + c1, kbl + d1b);
            GLOAD16(Vh + (size_t)r0 * SEQ + kb64 + c0, vbl + d0b);
            GLOAD16(Vh + (size_t)r1 * SEQ + kb64 + c1, vbl + d1b);
        }

        const char* kbuf = LdsB[buf];
        const char* vbuf = kbuf + 8192;

        bf16x8 kf[4][2];
        #pragma unroll
        for (int m = 0; m < 4; ++m) {
            const char* krow = kbuf + (16 * m + lr) * 128;
            kf[m][0] = *reinterpret_cast<const bf16x8*>(krow + ((lg * 16) ^ rswz));
            kf[m][1] = *reinterpret_cast<const bf16x8*>(krow + ((64 + lg * 16) ^ rswz));
        }

        const bool diag = (tile >= 2 * qt2);
        const int koff0 = (tile - 2 * qt2) * 64;

        unsigned dw[2][4][2];
        __builtin_amdgcn_s_setprio(1);
        #pragma unroll
        for (int fq = 0; fq < 2; ++fq) {
            f32x4 s[4];
            #pragma unroll
            for (int m = 0; m < 4; ++m) {
                s[m] = (f32x4){0.f, 0.f, 0.f, 0.f};
                s[m] = __builtin_amdgcn_mfma_f32_16x16x32_bf16(kf[m][0], qf[fq][0], s[m], 0, 0, 0);
                s[m] = __builtin_amdgcn_mfma_f32_16x16x32_bf16(kf[m][1], qf[fq][1], s[m], 0, 0, 0);
            }
            if (diag) {
                const int qloc = fq * 64 + w * 16 + lr;
                #pragma unroll
                for (int m = 0; m < 4; ++m)
                    #pragma unroll
                    for (int r = 0; r < 4; ++r)
                        if (koff0 + 16 * m + 4 * lg + r > qloc) s[m][r] = -1.0e38f;
            }
            float p[4][4];
            #pragma unroll
            for (int m = 0; m < 4; ++m) {
                #pragma unroll
                for (int r = 0; r < 4; ++r) p[m][r] = EXP2(s[m][r]);
                lsumv[fq] += (p[m][0] + p[m][1]) + (p[m][2] + p[m][3]);
                dw[fq][m][0] = cvt_pk_bf16(p[m][0], p[m][1]);
                dw[fq][m][1] = cvt_pk_bf16(p[m][2], p[m][3]);
            }
        }

        #pragma unroll
        for (int c = 0; c < 2; ++c) {
            union Pu { unsigned u[4]; bf16x8 v; } pb[2];
            #pragma unroll
            for (int fq = 0; fq < 2; ++fq) {
                pb[fq].u[0] = dw[fq][2 * c][0];     pb[fq].u[1] = dw[fq][2 * c][1];
                pb[fq].u[2] = dw[fq][2 * c + 1][0]; pb[fq].u[3] = dw[fq][2 * c + 1][1];
            }
            #pragma unroll
            for (int nb = 0; nb < 4; ++nb) {
                const char* vrow = vbuf + (16 * nb + lr) * 128;
                union Vu { s16x4 hv[2]; bf16x8 v; } vf;
                vf.hv[0] = *reinterpret_cast<const s16x4*>(
                    vrow + ((c * 64 + lg * 8) ^ rswz));
                vf.hv[1] = *reinterpret_cast<const s16x4*>(
                    vrow + ((c * 64 + 32 + lg * 8) ^ rswz));
                acc[0][nb] = __builtin_amdgcn_mfma_f32_16x16x32_bf16(
                    vf.v, pb[0].v, acc[0][nb], 0, 0, 0);
                acc[1][nb] = __builtin_amdgcn_mfma_f32_16x16x32_bf16(
                    vf.v, pb[1].v, acc[1][nb], 0, 0, 0);
            }
        }
        __builtin_amdgcn_s_setprio(0);
        // no end-of-tile barrier (next top barrier covers WAR on buf^1)
    }

    #pragma unroll
    for (int fq = 0; fq < 2; ++fq) {
        lsumv[fq] += __shfl_xor(lsumv[fq], 16);
        lsumv[fq] += __shfl_xor(lsumv[fq], 32);
    }

    if (nch == 1) {
        #pragma unroll
        for (int fq = 0; fq < 2; ++fq) {
            const float inv = 1.0f / lsumv[fq];
            const int qrow = q0 + fq * 64 + w * 16 + lr;
            u16* op = ctx + ((size_t)(b * SEQ) + qrow) * D_MODEL + h * 64 + 4 * lg;
            #pragma unroll
            for (int nb = 0; nb < 4; ++nb) {
                u16 t4[4];
                #pragma unroll
                for (int r = 0; r < 4; ++r) t4[r] = f2bf(acc[fq][nb][r] * inv);
                *reinterpret_cast<u64*>(op + 16 * nb) = *reinterpret_cast<u64*>(t4);
            }
        }
    } else {
        const int slot4 = ((bh * 12 + (qt2 - 4)) << 2) + ch;
        #pragma unroll
        for (int fq = 0; fq < 2; ++fq) {
            const int rloc = fq * 64 + w * 16 + lr;
            u16* op = Opart + (size_t)slot4 * 8192 + rloc * 64 + 4 * lg;
            #pragma unroll
            for (int nb = 0; nb < 4; ++nb) {
                u16 t4[4];
                #pragma unroll
                for (int r = 0; r < 4; ++r) t4[r] = f2bf(acc[fq][nb][r]);
                *reinterpret_cast<u64*>(op + 16 * nb) = *reinterpret_cast<u64*>(t4);
            }
            if (lg == 0) Lpart[slot4 * 128 + rloc] = lsumv[fq];
        }
    }
}

// Sum partials (<=4) for each (bh, qt2>=4), normalize, write ctx.
__global__ __launch_bounds__(128)
void attn_reduce_kernel(const u16* __restrict__ Opart,
                        const float* __restrict__ Lpart,
                        u16* __restrict__ ctx)
{
    const int blk = blockIdx.x;          // 0..383
    const int bh = blk / 12, idx = blk % 12;
    const int qt2 = idx + 4;
    const int nch = (2 * qt2 + 2 + 7) >> 3;
    const int t = threadIdx.x;           // query row in 128-tile
    const int b = bh >> 4, h = bh & (NUM_HEADS - 1);
    const int slot0 = (bh * 12 + idx) << 2;

    float acc[64] = {};
    float lt = 0.f;
    for (int ch = 0; ch < nch; ++ch) {
        const u16* op = Opart + (size_t)(slot0 + ch) * 8192 + t * 64;
        lt += Lpart[(slot0 + ch) * 128 + t];
        #pragma unroll
        for (int cchunk = 0; cchunk < 8; ++cchunk) {
            u16 v[8];
            *reinterpret_cast<int4*>(v) =
                *reinterpret_cast<const int4*>(op + cchunk * 8);
            #pragma unroll
            for (int j = 0; j < 8; ++j) acc[cchunk * 8 + j] += bf2f(v[j]);
        }
    }
    const float inv = 1.0f / lt;
    u16* orow = ctx + ((size_t)(b * SEQ) + qt2 * 128 + t) * D_MODEL + h * 64;
    #pragma unroll
    for (int cchunk = 0; cchunk < 8; ++cchunk) {
        u16 v[8];
        #pragma unroll
        for (int j = 0; j < 8; ++j) v[j] = f2bf(acc[cchunk * 8 + j] * inv);
        *reinterpret_cast<int4*>(orow + cchunk * 8) = *reinterpret_cast<int4*>(v);
    }
}

// ---------------------------------------------------------------------------

extern "C" void kernel_launch(void* const* d_in, const int* in_sizes, int n_in,
                              void* d_out, int out_size, void* d_ws, size_t ws_size,
                              hipStream_t stream)
{
    const float* x  = (const float*)d_in[0];
    const float* Wq = (const float*)d_in[1];
    const float* Wk = (const float*)d_in[2];
    const float* Wv = (const float*)d_in[3];
    const float* Wo = (const float*)d_in[4];
    const float* bo = (const float*)d_in[5];
    float* out = (float*)d_out;

    u16* xb   = (u16*)d_ws;                               // 4096*1024
    u16* wqkv = xb   + (size_t)MTOT * D_MODEL;            // 3072*1024
    u16* wob  = wqkv + (size_t)3 * D_MODEL * D_MODEL;     // 1024*1024
    u16* Qw   = wob  + (size_t)D_MODEL * D_MODEL;         // [b,h,s,d] (pre-scaled)
    u16* Kw   = Qw   + (size_t)MTOT * D_MODEL;            // [b,h,s,d]
    u16* Vtw  = Kw   + (size_t)MTOT * D_MODEL;            // [b,h,d,s]
    u16* ctxb = Vtw  + (size_t)MTOT * D_MODEL;            // [4096][1024]
    u16* Opart = ctxb + (size_t)MTOT * D_MODEL;           // 1536 slots x 8192
    float* Lpart = (float*)(Opart + (size_t)1536 * 8192); // 1536 x 128

    cast_all_kernel<<<4096, 256, 0, stream>>>(x, Wq, Wk, Wv, Wo, xb);

    gemm_qkv_kernel<<<dim3(768), 512, 0, stream>>>(xb, wqkv, Qw, Kw, Vtw);

    attn_kernel<<<dim3(1280), 256, 0, stream>>>(Qw, Kw, Vtw, ctxb, Opart, Lpart);
    attn_reduce_kernel<<<dim3(384), 128, 0, stream>>>(Opart, Lpart, ctxb);

    gemm_out_kernel<<<dim3(256), 512, 0, stream>>>(ctxb, wob, bo, out);
}

// Round 20
// 110.648 us; speedup vs baseline: 1.0380x; 1.0072x over previous
//
#include <hip/hip_runtime.h>

#define D_MODEL 1024
#define NUM_HEADS 16
#define HEAD_DIM 64
#define BATCH 2
#define SEQ 2048
#define MTOT (BATCH * SEQ)   // 4096

typedef __attribute__((ext_vector_type(8))) short bf16x8;   // 8 bf16 in 4 VGPRs
typedef __attribute__((ext_vector_type(4))) short s16x4;
typedef __attribute__((ext_vector_type(4))) float f32x4;
typedef unsigned short u16;
typedef unsigned long long u64;

__device__ __forceinline__ u16 f2bf(float f) {
    unsigned u = __float_as_uint(f);
    return (u16)((u + 0x7FFFu + ((u >> 16) & 1u)) >> 16);   // RNE, finite data
}
__device__ __forceinline__ float bf2f(u16 v) {
    return __uint_as_float((unsigned)v << 16);
}

__device__ __forceinline__ unsigned cvt_pk_bf16(float lo, float hi) {
    unsigned r;
    asm volatile("v_cvt_pk_bf16_f32 %0, %1, %2" : "=v"(r) : "v"(lo), "v"(hi));
    return r;
}

#if __has_builtin(__builtin_amdgcn_exp2f)
#define EXP2(x) __builtin_amdgcn_exp2f(x)
#else
#define EXP2(x) exp2f(x)
#endif

#define GLOAD16(gp, lp) __builtin_amdgcn_global_load_lds(                      \
    (const __attribute__((address_space(1))) void*)(gp),                       \
    (__attribute__((address_space(3))) void*)(lp), 16, 0, 0)

// ---------------------------------------------------------------------------
// One merged fp32 -> bf16 cast: x | Wqkv | Wo into contiguous ws region.
// ---------------------------------------------------------------------------
__global__ __launch_bounds__(256)
void cast_all_kernel(const float* __restrict__ x,  const float* __restrict__ Wq,
                     const float* __restrict__ Wk, const float* __restrict__ Wv,
                     const float* __restrict__ Wo, u16* __restrict__ dst)
{
    const int i = blockIdx.x * 256 + threadIdx.x;   // 1048576 groups of 8
    const float* src;
    int j;
    if (i < 524288) { src = x; j = i; }
    else if (i < 917504) {
        const int k = i - 524288;
        const int z = k >> 17;
        src = (z == 0) ? Wq : (z == 1) ? Wk : Wv;
        j = k & 0x1FFFF;
    } else { src = Wo; j = i - 917504; }
    const float4* s = reinterpret_cast<const float4*>(src) + (size_t)j * 2;
    float4 a = s[0], b = s[1];
    u16 tmp[8] = {f2bf(a.x), f2bf(a.y), f2bf(a.z), f2bf(a.w),
                  f2bf(b.x), f2bf(b.y), f2bf(b.z), f2bf(b.w)};
    *reinterpret_cast<int4*>(dst + (size_t)i * 8) = *reinterpret_cast<int4*>(tmp);
}

// ---------------------------------------------------------------------------
// QKV GEMM, pipelined, 8-wave: BM=BN=128, BK=32, 512 threads (2Mx4N,
// 64x32/wave), triple-buffered 48KB LDS, distance-2, counted vmcnt(2),
// grid 768 = 3 blocks/CU, no tail. Epilogue: Q pre-scaled 0.125*log2e,
// K [b,h,s,d], V^T [b,h,d,s].
// ---------------------------------------------------------------------------
__global__ __launch_bounds__(512, 6)
void gemm_qkv_kernel(const u16* __restrict__ A, const u16* __restrict__ B,
                     u16* __restrict__ Qo, u16* __restrict__ Ko, u16* __restrict__ Vt)
{
    __shared__ u16 Al[3][128 * 32];   // 3 x 8 KB
    __shared__ u16 Bl[3][128 * 32];   // 3 x 8 KB

    const int tid = threadIdx.x;
    const int l = tid & 63;
    const int w = tid >> 6;            // 0..7
    const int wm = w >> 2, wn = w & 3; // 2M x 4N
    const int lr = l & 15, lg = l >> 4;

    const int bid = blockIdx.x;                    // 0..767, 768%8==0
    const int swz = (bid & 7) * 96 + (bid >> 3);   // XCD-bijective
    const int mb = swz / 24, nbv = swz % 24;       // 32 x 24 blocks
    const int m0 = mb * 128, n0 = nbv * 128;

    const int arow = tid >> 2;                               // 0..127
    const int acol = ((tid & 3) ^ ((arow >> 1) & 3)) * 8;    // inv-swizzled col
    const int dstq = tid * 8;                                // u16 units
    const int rsw  = (lr >> 1) & 3;                          // read slot XOR

    f32x4 acc[4][2];
    #pragma unroll
    for (int i = 0; i < 4; ++i)
        #pragma unroll
        for (int j = 0; j < 2; ++j) acc[i][j] = (f32x4){0.f, 0.f, 0.f, 0.f};

    #pragma unroll
    for (int t = 0; t < 2; ++t) {
        const int k0 = t * 32;
        GLOAD16(A + (size_t)(m0 + arow) * D_MODEL + k0 + acol, &Al[t][dstq]);
        GLOAD16(B + (size_t)(n0 + arow) * D_MODEL + k0 + acol, &Bl[t][dstq]);
    }

    int cb = 0;                        // current buffer = t % 3
    for (int t = 0; t < 32; ++t) {
        if (t < 31) asm volatile("s_waitcnt vmcnt(2)" ::: "memory");
        else        asm volatile("s_waitcnt vmcnt(0)" ::: "memory");
        __builtin_amdgcn_s_barrier();

        if (t + 2 < 32) {
            const int sb = (cb >= 1) ? cb - 1 : cb + 2;   // (t+2)%3
            const int k0 = (t + 2) * 32;
            GLOAD16(A + (size_t)(m0 + arow) * D_MODEL + k0 + acol, &Al[sb][dstq]);
            GLOAD16(B + (size_t)(n0 + arow) * D_MODEL + k0 + acol, &Bl[sb][dstq]);
        }

        const u16* __restrict__ Ab = Al[cb];
        const u16* __restrict__ Bb = Bl[cb];
        bf16x8 af[4], bfr[2];
        #pragma unroll
        for (int i = 0; i < 4; ++i)
            af[i] = *reinterpret_cast<const bf16x8*>(
                &Ab[(wm * 64 + i * 16 + lr) * 32 + ((lg ^ rsw) * 8)]);
        #pragma unroll
        for (int j = 0; j < 2; ++j)
            bfr[j] = *reinterpret_cast<const bf16x8*>(
                &Bb[(wn * 32 + j * 16 + lr) * 32 + ((lg ^ rsw) * 8)]);

        __builtin_amdgcn_s_setprio(1);
        #pragma unroll
        for (int i = 0; i < 4; ++i)
            #pragma unroll
            for (int j = 0; j < 2; ++j)
                acc[i][j] = __builtin_amdgcn_mfma_f32_16x16x32_bf16(
                    af[i], bfr[j], acc[i][j], 0, 0, 0);
        __builtin_amdgcn_s_setprio(0);

        cb = (cb == 2) ? 0 : cb + 1;
    }

    const int z = (n0 >> 10);           // 0=Q 1=K 2=V (uniform per block)
    if (z < 2) {
        #pragma unroll
        for (int i = 0; i < 4; ++i) {
            #pragma unroll
            for (int r = 0; r < 4; ++r) {
                const int m = m0 + wm * 64 + i * 16 + lg * 4 + r;
                const int bb = m >> 11, s = m & (SEQ - 1);
                #pragma unroll
                for (int j = 0; j < 2; ++j) {
                    const int c = n0 + wn * 32 + j * 16 + lr;
                    const int cc = c & 1023, h = cc >> 6, d = cc & 63;
                    const size_t idx = ((size_t)(bb * NUM_HEADS + h) * SEQ + s) * 64 + d;
                    if (z == 0) Qo[idx] = f2bf(acc[i][j][r] * 0.18033688f);  // 1/8*log2e
                    else        Ko[idx] = f2bf(acc[i][j][r]);
                }
            }
        }
    } else {
        #pragma unroll
        for (int i = 0; i < 4; ++i) {
            const int mbase = m0 + wm * 64 + i * 16 + lg * 4;   // 4 consecutive s
            const int bb = mbase >> 11, s = mbase & (SEQ - 1);
            #pragma unroll
            for (int j = 0; j < 2; ++j) {
                const int c = n0 + wn * 32 + j * 16 + lr;
                const int cc = c & 1023, h = cc >> 6, d = cc & 63;
                u16 t4[4];
                #pragma unroll
                for (int r = 0; r < 4; ++r) t4[r] = f2bf(acc[i][j][r]);
                *reinterpret_cast<u64*>(
                    &Vt[((size_t)(bb * NUM_HEADS + h) * 64 + d) * SEQ + s]) =
                    *reinterpret_cast<u64*>(t4);
            }
        }
    }
}

// ---------------------------------------------------------------------------
// Output GEMM, pipelined, 8-wave: ctx[4096][1024] @ Wo^T + bo, fp32 out.
// Same template (512 thr, 2Mx4N, vmcnt(2), 48KB 3-buf). Grid 256 = 1/CU.
// ---------------------------------------------------------------------------
__global__ __launch_bounds__(512, 2)
void gemm_out_kernel(const u16* __restrict__ A, const u16* __restrict__ B,
                     const float* __restrict__ bias, float* __restrict__ out)
{
    __shared__ u16 Al[3][128 * 32];   // 3 x 8 KB
    __shared__ u16 Bl[3][128 * 32];   // 3 x 8 KB

    const int tid = threadIdx.x;
    const int l = tid & 63;
    const int w = tid >> 6;            // 0..7
    const int wm = w >> 2, wn = w & 3; // 2M x 4N
    const int lr = l & 15, lg = l >> 4;

    const int bid = blockIdx.x;                    // 0..255, 256%8==0
    const int swz = (bid & 7) * 32 + (bid >> 3);   // XCD-bijective
    const int mb = swz >> 3, nb = swz & 7;         // 32 x 8 blocks
    const int m0 = mb * 128, n0 = nb * 128;

    const int arow = tid >> 2;                               // 0..127
    const int acol = ((tid & 3) ^ ((arow >> 1) & 3)) * 8;
    const int dstq = tid * 8;                                // u16 units
    const int rsw  = (lr >> 1) & 3;

    f32x4 acc[4][2];
    #pragma unroll
    for (int i = 0; i < 4; ++i)
        #pragma unroll
        for (int j = 0; j < 2; ++j) acc[i][j] = (f32x4){0.f, 0.f, 0.f, 0.f};

    #pragma unroll
    for (int t = 0; t < 2; ++t) {
        const int k0 = t * 32;
        GLOAD16(A + (size_t)(m0 + arow) * D_MODEL + k0 + acol, &Al[t][dstq]);
        GLOAD16(B + (size_t)(n0 + arow) * D_MODEL + k0 + acol, &Bl[t][dstq]);
    }

    int cb = 0;
    for (int t = 0; t < 32; ++t) {
        if (t < 31) asm volatile("s_waitcnt vmcnt(2)" ::: "memory");
        else        asm volatile("s_waitcnt vmcnt(0)" ::: "memory");
        __builtin_amdgcn_s_barrier();

        if (t + 2 < 32) {
            const int sb = (cb >= 1) ? cb - 1 : cb + 2;   // (t+2)%3
            const int k0 = (t + 2) * 32;
            GLOAD16(A + (size_t)(m0 + arow) * D_MODEL + k0 + acol, &Al[sb][dstq]);
            GLOAD16(B + (size_t)(n0 + arow) * D_MODEL + k0 + acol, &Bl[sb][dstq]);
        }

        const u16* __restrict__ Ab = Al[cb];
        const u16* __restrict__ Bb = Bl[cb];
        bf16x8 af[4], bfr[2];
        #pragma unroll
        for (int i = 0; i < 4; ++i)
            af[i] = *reinterpret_cast<const bf16x8*>(
                &Ab[(wm * 64 + i * 16 + lr) * 32 + ((lg ^ rsw) * 8)]);
        #pragma unroll
        for (int j = 0; j < 2; ++j)
            bfr[j] = *reinterpret_cast<const bf16x8*>(
                &Bb[(wn * 32 + j * 16 + lr) * 32 + ((lg ^ rsw) * 8)]);

        __builtin_amdgcn_s_setprio(1);
        #pragma unroll
        for (int i = 0; i < 4; ++i)
            #pragma unroll
            for (int j = 0; j < 2; ++j)
                acc[i][j] = __builtin_amdgcn_mfma_f32_16x16x32_bf16(
                    af[i], bfr[j], acc[i][j], 0, 0, 0);
        __builtin_amdgcn_s_setprio(0);

        cb = (cb == 2) ? 0 : cb + 1;
    }

    #pragma unroll
    for (int i = 0; i < 4; ++i) {
        #pragma unroll
        for (int r = 0; r < 4; ++r) {
            const int m = m0 + wm * 64 + i * 16 + lg * 4 + r;
            #pragma unroll
            for (int j = 0; j < 2; ++j) {
                const int c = n0 + wn * 32 + j * 16 + lr;
                out[(size_t)m * D_MODEL + c] = acc[i][j][r] + bias[c];
            }
        }
    }
}

// ---------------------------------------------------------------------------
// Split-S MFMA causal flash attention, QBLK=128 (best measured version),
// WITHOUT setprio (m190: setprio is null-to-negative in barrier-locked
// lockstep structures; holding prio 1 across the tile body can starve
// co-resident blocks' DMA issue). Otherwise byte-identical.
// ---------------------------------------------------------------------------
__device__ __forceinline__ void map_pair128(int p, int& qt2, int& ch) {
    if (p < 16)      { qt2 = 15 - (p >> 2); ch = p & 3; }
    else if (p < 28) { int t = p - 16; qt2 = 11 - t / 3; ch = t % 3; }
    else if (p < 36) { int t = p - 28; qt2 = 7 - (t >> 1); ch = t & 1; }
    else             { qt2 = 39 - p; ch = 0; }
}

__global__ __launch_bounds__(256)
void attn_kernel(const u16* __restrict__ Q, const u16* __restrict__ K,
                 const u16* __restrict__ Vt, u16* __restrict__ ctx,
                 u16* __restrict__ Opart, float* __restrict__ Lpart)
{
    __shared__ char LdsB[2][16384];   // per buf: K 8KB @0, V 8KB @8192

    const int tid = threadIdx.x;
    const int l = tid & 63;
    const int w = tid >> 6;
    const int lr = l & 15;
    const int lg = l >> 4;

    const int xcd  = blockIdx.x & 7;
    const int slot = blockIdx.x >> 3;          // 0..159
    const int bh   = xcd * 4 + slot / 40;      // 4 heads per XCD chunk
    int qt2, ch;
    map_pair128(slot % 40, qt2, ch);

    const int ntiles = 2 * qt2 + 2;
    const int nch  = (ntiles + 7) >> 3;        // ceil(ntiles/8)
    const int base = ntiles / nch, rem = ntiles % nch;
    const int start = ch * base + (ch < rem ? ch : rem);
    const int cnt   = base + (ch < rem ? 1 : 0);

    const size_t hbase = (size_t)bh * SEQ * 64;
    const int b = bh >> 4, h = bh & (NUM_HEADS - 1);
    const u16* __restrict__ Kh = K + hbase;
    const u16* __restrict__ Vh = Vt + hbase;
    const int q0 = qt2 * 128;

    const int r0 = tid >> 3;
    const int c0 = ((tid & 7) ^ (r0 & 7)) * 8;
    const int r1 = (256 + tid) >> 3;
    const int c1 = ((tid & 7) ^ (r1 & 7)) * 8;
    const int d0b = tid * 16;
    const int d1b = 4096 + tid * 16;
    const int rswz = (lr & 7) << 4;

    bf16x8 qf[2][2];
    #pragma unroll
    for (int fq = 0; fq < 2; ++fq) {
        const u16* qp = Q + hbase + (size_t)(q0 + fq * 64 + w * 16 + lr) * 64 + lg * 8;
        qf[fq][0] = *reinterpret_cast<const bf16x8*>(qp);
        qf[fq][1] = *reinterpret_cast<const bf16x8*>(qp + 32);
    }
    asm volatile("s_waitcnt vmcnt(0)" ::: "memory");   // keep stage-FIFO math exact

    f32x4 acc[2][4];
    #pragma unroll
    for (int fq = 0; fq < 2; ++fq)
        #pragma unroll
        for (int nb = 0; nb < 4; ++nb) acc[fq][nb] = (f32x4){0.f, 0.f, 0.f, 0.f};
    float lsumv[2] = {0.f, 0.f};

    {   // prologue: stage tile `start` -> buf 0 (4 loads in flight)
        char* kb = LdsB[0];
        char* vb = LdsB[0] + 8192;
        const int kb64 = start * 64;
        GLOAD16(Kh + (size_t)(kb64 + r0) * 64 + c0, kb + d0b);
        GLOAD16(Kh + (size_t)(kb64 + r1) * 64 + c1, kb + d1b);
        GLOAD16(Vh + (size_t)r0 * SEQ + kb64 + c0, vb + d0b);
        GLOAD16(Vh + (size_t)r1 * SEQ + kb64 + c1, vb + d1b);
    }

    for (int it = 0; it < cnt; ++it) {
        const int tile = start + it;
        const int buf = it & 1;

        // single per-tile checkpoint: tile `it` ready, publish to all waves
        asm volatile("s_waitcnt vmcnt(0)" ::: "memory");
        __builtin_amdgcn_s_barrier();

        if (it < cnt - 1) {                      // issue next tile's DMA now
            const int kb64 = (tile + 1) * 64;
            char* kbl = LdsB[buf ^ 1];
            char* vbl = kbl + 8192;
            GLOAD16(Kh + (size_t)(kb64 + r0) * 64 + c0, kbl + d0b);
            GLOAD16(Kh + (size_t)(kb64 + r1) * 64 + c1, kbl + d1b);
            GLOAD16(Vh + (size_t)r0 * SEQ + kb64 + c0, vbl + d0b);
            GLOAD16(Vh + (size_t)r1 * SEQ + kb64 + c1, vbl + d1b);
        }

        const char* kbuf = LdsB[buf];
        const char* vbuf = kbuf + 8192;

        bf16x8 kf[4][2];
        #pragma unroll
        for (int m = 0; m < 4; ++m) {
            const char* krow = kbuf + (16 * m + lr) * 128;
            kf[m][0] = *reinterpret_cast<const bf16x8*>(krow + ((lg * 16) ^ rswz));
            kf[m][1] = *reinterpret_cast<const bf16x8*>(krow + ((64 + lg * 16) ^ rswz));
        }

        const bool diag = (tile >= 2 * qt2);
        const int koff0 = (tile - 2 * qt2) * 64;

        unsigned dw[2][4][2];
        #pragma unroll
        for (int fq = 0; fq < 2; ++fq) {
            f32x4 s[4];
            #pragma unroll
            for (int m = 0; m < 4; ++m) {
                s[m] = (f32x4){0.f, 0.f, 0.f, 0.f};
                s[m] = __builtin_amdgcn_mfma_f32_16x16x32_bf16(kf[m][0], qf[fq][0], s[m], 0, 0, 0);
                s[m] = __builtin_amdgcn_mfma_f32_16x16x32_bf16(kf[m][1], qf[fq][1], s[m], 0, 0, 0);
            }
            if (diag) {
                const int qloc = fq * 64 + w * 16 + lr;
                #pragma unroll
                for (int m = 0; m < 4; ++m)
                    #pragma unroll
                    for (int r = 0; r < 4; ++r)
                        if (koff0 + 16 * m + 4 * lg + r > qloc) s[m][r] = -1.0e38f;
            }
            float p[4][4];
            #pragma unroll
            for (int m = 0; m < 4; ++m) {
                #pragma unroll
                for (int r = 0; r < 4; ++r) p[m][r] = EXP2(s[m][r]);
                lsumv[fq] += (p[m][0] + p[m][1]) + (p[m][2] + p[m][3]);
                dw[fq][m][0] = cvt_pk_bf16(p[m][0], p[m][1]);
                dw[fq][m][1] = cvt_pk_bf16(p[m][2], p[m][3]);
            }
        }

        #pragma unroll
        for (int c = 0; c < 2; ++c) {
            union Pu { unsigned u[4]; bf16x8 v; } pb[2];
            #pragma unroll
            for (int fq = 0; fq < 2; ++fq) {
                pb[fq].u[0] = dw[fq][2 * c][0];     pb[fq].u[1] = dw[fq][2 * c][1];
                pb[fq].u[2] = dw[fq][2 * c + 1][0]; pb[fq].u[3] = dw[fq][2 * c + 1][1];
            }
            #pragma unroll
            for (int nb = 0; nb < 4; ++nb) {
                const char* vrow = vbuf + (16 * nb + lr) * 128;
                union Vu { s16x4 hv[2]; bf16x8 v; } vf;
                vf.hv[0] = *reinterpret_cast<const s16x4*>(
                    vrow + ((c * 64 + lg * 8) ^ rswz));
                vf.hv[1] = *reinterpret_cast<const s16x4*>(
                    vrow + ((c * 64 + 32 + lg * 8) ^ rswz));
                acc[0][nb] = __builtin_amdgcn_mfma_f32_16x16x32_bf16(
                    vf.v, pb[0].v, acc[0][nb], 0, 0, 0);
                acc[1][nb] = __builtin_amdgcn_mfma_f32_16x16x32_bf16(
                    vf.v, pb[1].v, acc[1][nb], 0, 0, 0);
            }
        }
        // no end-of-tile barrier (next top barrier covers WAR on buf^1)
    }

    #pragma unroll
    for (int fq = 0; fq < 2; ++fq) {
        lsumv[fq] += __shfl_xor(lsumv[fq], 16);
        lsumv[fq] += __shfl_xor(lsumv[fq], 32);
    }

    if (nch == 1) {
        #pragma unroll
        for (int fq = 0; fq < 2; ++fq) {
            const float inv = 1.0f / lsumv[fq];
            const int qrow = q0 + fq * 64 + w * 16 + lr;
            u16* op = ctx + ((size_t)(b * SEQ) + qrow) * D_MODEL + h * 64 + 4 * lg;
            #pragma unroll
            for (int nb = 0; nb < 4; ++nb) {
                u16 t4[4];
                #pragma unroll
                for (int r = 0; r < 4; ++r) t4[r] = f2bf(acc[fq][nb][r] * inv);
                *reinterpret_cast<u64*>(op + 16 * nb) = *reinterpret_cast<u64*>(t4);
            }
        }
    } else {
        const int slot4 = ((bh * 12 + (qt2 - 4)) << 2) + ch;
        #pragma unroll
        for (int fq = 0; fq < 2; ++fq) {
            const int rloc = fq * 64 + w * 16 + lr;
            u16* op = Opart + (size_t)slot4 * 8192 + rloc * 64 + 4 * lg;
            #pragma unroll
            for (int nb = 0; nb < 4; ++nb) {
                u16 t4[4];
                #pragma unroll
                for (int r = 0; r < 4; ++r) t4[r] = f2bf(acc[fq][nb][r]);
                *reinterpret_cast<u64*>(op + 16 * nb) = *reinterpret_cast<u64*>(t4);
            }
            if (lg == 0) Lpart[slot4 * 128 + rloc] = lsumv[fq];
        }
    }
}

// Sum partials (<=4) for each (bh, qt2>=4), normalize, write ctx.
__global__ __launch_bounds__(128)
void attn_reduce_kernel(const u16* __restrict__ Opart,
                        const float* __restrict__ Lpart,
                        u16* __restrict__ ctx)
{
    const int blk = blockIdx.x;          // 0..383
    const int bh = blk / 12, idx = blk % 12;
    const int qt2 = idx + 4;
    const int nch = (2 * qt2 + 2 + 7) >> 3;
    const int t = threadIdx.x;           // query row in 128-tile
    const int b = bh >> 4, h = bh & (NUM_HEADS - 1);
    const int slot0 = (bh * 12 + idx) << 2;

    float acc[64] = {};
    float lt = 0.f;
    for (int ch = 0; ch < nch; ++ch) {
        const u16* op = Opart + (size_t)(slot0 + ch) * 8192 + t * 64;
        lt += Lpart[(slot0 + ch) * 128 + t];
        #pragma unroll
        for (int cchunk = 0; cchunk < 8; ++cchunk) {
            u16 v[8];
            *reinterpret_cast<int4*>(v) =
                *reinterpret_cast<const int4*>(op + cchunk * 8);
            #pragma unroll
            for (int j = 0; j < 8; ++j) acc[cchunk * 8 + j] += bf2f(v[j]);
        }
    }
    const float inv = 1.0f / lt;
    u16* orow = ctx + ((size_t)(b * SEQ) + qt2 * 128 + t) * D_MODEL + h * 64;
    #pragma unroll
    for (int cchunk = 0; cchunk < 8; ++cchunk) {
        u16 v[8];
        #pragma unroll
        for (int j = 0; j < 8; ++j) v[j] = f2bf(acc[cchunk * 8 + j] * inv);
        *reinterpret_cast<int4*>(orow + cchunk * 8) = *reinterpret_cast<int4*>(v);
    }
}

// ---------------------------------------------------------------------------

extern "C" void kernel_launch(void* const* d_in, const int* in_sizes, int n_in,
                              void* d_out, int out_size, void* d_ws, size_t ws_size,
                              hipStream_t stream)
{
    const float* x  = (const float*)d_in[0];
    const float* Wq = (const float*)d_in[1];
    const float* Wk = (const float*)d_in[2];
    const float* Wv = (const float*)d_in[3];
    const float* Wo = (const float*)d_in[4];
    const float* bo = (const float*)d_in[5];
    float* out = (float*)d_out;

    u16* xb   = (u16*)d_ws;                               // 4096*1024
    u16* wqkv = xb   + (size_t)MTOT * D_MODEL;            // 3072*1024
    u16* wob  = wqkv + (size_t)3 * D_MODEL * D_MODEL;     // 1024*1024
    u16* Qw   = wob  + (size_t)D_MODEL * D_MODEL;         // [b,h,s,d] (pre-scaled)
    u16* Kw   = Qw   + (size_t)MTOT * D_MODEL;            // [b,h,s,d]
    u16* Vtw  = Kw   + (size_t)MTOT * D_MODEL;            // [b,h,d,s]
    u16* ctxb = Vtw  + (size_t)MTOT * D_MODEL;            // [4096][1024]
    u16* Opart = ctxb + (size_t)MTOT * D_MODEL;           // 1536 slots x 8192
    float* Lpart = (float*)(Opart + (size_t)1536 * 8192); // 1536 x 128

    cast_all_kernel<<<4096, 256, 0, stream>>>(x, Wq, Wk, Wv, Wo, xb);

    gemm_qkv_kernel<<<dim3(768), 512, 0, stream>>>(xb, wqkv, Qw, Kw, Vtw);

    attn_kernel<<<dim3(1280), 256, 0, stream>>>(Qw, Kw, Vtw, ctxb, Opart, Lpart);
    attn_reduce_kernel<<<dim3(384), 128, 0, stream>>>(Opart, Lpart, ctxb);

    gemm_out_kernel<<<dim3(256), 512, 0, stream>>>(ctxb, wob, bo, out);
}

// Round 21
// 110.491 us; speedup vs baseline: 1.0395x; 1.0014x over previous
//
#include <hip/hip_runtime.h>

#define D_MODEL 1024
#define NUM_HEADS 16
#define HEAD_DIM 64
#define BATCH 2
#define SEQ 2048
#define MTOT (BATCH * SEQ)   // 4096

typedef __attribute__((ext_vector_type(8))) short bf16x8;   // 8 bf16 in 4 VGPRs
typedef __attribute__((ext_vector_type(4))) short s16x4;
typedef __attribute__((ext_vector_type(4))) float f32x4;
typedef unsigned short u16;
typedef unsigned long long u64;

__device__ __forceinline__ u16 f2bf(float f) {
    unsigned u = __float_as_uint(f);
    return (u16)((u + 0x7FFFu + ((u >> 16) & 1u)) >> 16);   // RNE, finite data
}
__device__ __forceinline__ float bf2f(u16 v) {
    return __uint_as_float((unsigned)v << 16);
}

__device__ __forceinline__ unsigned cvt_pk_bf16(float lo, float hi) {
    unsigned r;
    asm volatile("v_cvt_pk_bf16_f32 %0, %1, %2" : "=v"(r) : "v"(lo), "v"(hi));
    return r;
}

#if __has_builtin(__builtin_amdgcn_exp2f)
#define EXP2(x) __builtin_amdgcn_exp2f(x)
#else
#define EXP2(x) exp2f(x)
#endif

#define GLOAD16(gp, lp) __builtin_amdgcn_global_load_lds(                      \
    (const __attribute__((address_space(1))) void*)(gp),                       \
    (__attribute__((address_space(3))) void*)(lp), 16, 0, 0)

// ---------------------------------------------------------------------------
// One merged fp32 -> bf16 cast: x | Wqkv | Wo into contiguous ws region.
// ---------------------------------------------------------------------------
__global__ __launch_bounds__(256)
void cast_all_kernel(const float* __restrict__ x,  const float* __restrict__ Wq,
                     const float* __restrict__ Wk, const float* __restrict__ Wv,
                     const float* __restrict__ Wo, u16* __restrict__ dst)
{
    const int i = blockIdx.x * 256 + threadIdx.x;   // 1048576 groups of 8
    const float* src;
    int j;
    if (i < 524288) { src = x; j = i; }
    else if (i < 917504) {
        const int k = i - 524288;
        const int z = k >> 17;
        src = (z == 0) ? Wq : (z == 1) ? Wk : Wv;
        j = k & 0x1FFFF;
    } else { src = Wo; j = i - 917504; }
    const float4* s = reinterpret_cast<const float4*>(src) + (size_t)j * 2;
    float4 a = s[0], b = s[1];
    u16 tmp[8] = {f2bf(a.x), f2bf(a.y), f2bf(a.z), f2bf(a.w),
                  f2bf(b.x), f2bf(b.y), f2bf(b.z), f2bf(b.w)};
    *reinterpret_cast<int4*>(dst + (size_t)i * 8) = *reinterpret_cast<int4*>(tmp);
}

// ---------------------------------------------------------------------------
// QKV GEMM, pipelined, 8-wave: BM=BN=128, BK=32, 512 threads (2Mx4N,
// 64x32/wave), triple-buffered 48KB LDS, distance-2, counted vmcnt(2),
// grid 768 = 3 blocks/CU, no tail. No setprio (m190: negative in lockstep).
// Epilogue: Q pre-scaled 0.125*log2e, K [b,h,s,d], V^T [b,h,d,s].
// ---------------------------------------------------------------------------
__global__ __launch_bounds__(512, 6)
void gemm_qkv_kernel(const u16* __restrict__ A, const u16* __restrict__ B,
                     u16* __restrict__ Qo, u16* __restrict__ Ko, u16* __restrict__ Vt)
{
    __shared__ u16 Al[3][128 * 32];   // 3 x 8 KB
    __shared__ u16 Bl[3][128 * 32];   // 3 x 8 KB

    const int tid = threadIdx.x;
    const int l = tid & 63;
    const int w = tid >> 6;            // 0..7
    const int wm = w >> 2, wn = w & 3; // 2M x 4N
    const int lr = l & 15, lg = l >> 4;

    const int bid = blockIdx.x;                    // 0..767, 768%8==0
    const int swz = (bid & 7) * 96 + (bid >> 3);   // XCD-bijective
    const int mb = swz / 24, nbv = swz % 24;       // 32 x 24 blocks
    const int m0 = mb * 128, n0 = nbv * 128;

    const int arow = tid >> 2;                               // 0..127
    const int acol = ((tid & 3) ^ ((arow >> 1) & 3)) * 8;    // inv-swizzled col
    const int dstq = tid * 8;                                // u16 units
    const int rsw  = (lr >> 1) & 3;                          // read slot XOR

    f32x4 acc[4][2];
    #pragma unroll
    for (int i = 0; i < 4; ++i)
        #pragma unroll
        for (int j = 0; j < 2; ++j) acc[i][j] = (f32x4){0.f, 0.f, 0.f, 0.f};

    #pragma unroll
    for (int t = 0; t < 2; ++t) {
        const int k0 = t * 32;
        GLOAD16(A + (size_t)(m0 + arow) * D_MODEL + k0 + acol, &Al[t][dstq]);
        GLOAD16(B + (size_t)(n0 + arow) * D_MODEL + k0 + acol, &Bl[t][dstq]);
    }

    int cb = 0;                        // current buffer = t % 3
    for (int t = 0; t < 32; ++t) {
        if (t < 31) asm volatile("s_waitcnt vmcnt(2)" ::: "memory");
        else        asm volatile("s_waitcnt vmcnt(0)" ::: "memory");
        __builtin_amdgcn_s_barrier();

        if (t + 2 < 32) {
            const int sb = (cb >= 1) ? cb - 1 : cb + 2;   // (t+2)%3
            const int k0 = (t + 2) * 32;
            GLOAD16(A + (size_t)(m0 + arow) * D_MODEL + k0 + acol, &Al[sb][dstq]);
            GLOAD16(B + (size_t)(n0 + arow) * D_MODEL + k0 + acol, &Bl[sb][dstq]);
        }

        const u16* __restrict__ Ab = Al[cb];
        const u16* __restrict__ Bb = Bl[cb];
        bf16x8 af[4], bfr[2];
        #pragma unroll
        for (int i = 0; i < 4; ++i)
            af[i] = *reinterpret_cast<const bf16x8*>(
                &Ab[(wm * 64 + i * 16 + lr) * 32 + ((lg ^ rsw) * 8)]);
        #pragma unroll
        for (int j = 0; j < 2; ++j)
            bfr[j] = *reinterpret_cast<const bf16x8*>(
                &Bb[(wn * 32 + j * 16 + lr) * 32 + ((lg ^ rsw) * 8)]);

        #pragma unroll
        for (int i = 0; i < 4; ++i)
            #pragma unroll
            for (int j = 0; j < 2; ++j)
                acc[i][j] = __builtin_amdgcn_mfma_f32_16x16x32_bf16(
                    af[i], bfr[j], acc[i][j], 0, 0, 0);

        cb = (cb == 2) ? 0 : cb + 1;
    }

    const int z = (n0 >> 10);           // 0=Q 1=K 2=V (uniform per block)
    if (z < 2) {
        #pragma unroll
        for (int i = 0; i < 4; ++i) {
            #pragma unroll
            for (int r = 0; r < 4; ++r) {
                const int m = m0 + wm * 64 + i * 16 + lg * 4 + r;
                const int bb = m >> 11, s = m & (SEQ - 1);
                #pragma unroll
                for (int j = 0; j < 2; ++j) {
                    const int c = n0 + wn * 32 + j * 16 + lr;
                    const int cc = c & 1023, h = cc >> 6, d = cc & 63;
                    const size_t idx = ((size_t)(bb * NUM_HEADS + h) * SEQ + s) * 64 + d;
                    if (z == 0) Qo[idx] = f2bf(acc[i][j][r] * 0.18033688f);  // 1/8*log2e
                    else        Ko[idx] = f2bf(acc[i][j][r]);
                }
            }
        }
    } else {
        #pragma unroll
        for (int i = 0; i < 4; ++i) {
            const int mbase = m0 + wm * 64 + i * 16 + lg * 4;   // 4 consecutive s
            const int bb = mbase >> 11, s = mbase & (SEQ - 1);
            #pragma unroll
            for (int j = 0; j < 2; ++j) {
                const int c = n0 + wn * 32 + j * 16 + lr;
                const int cc = c & 1023, h = cc >> 6, d = cc & 63;
                u16 t4[4];
                #pragma unroll
                for (int r = 0; r < 4; ++r) t4[r] = f2bf(acc[i][j][r]);
                *reinterpret_cast<u64*>(
                    &Vt[((size_t)(bb * NUM_HEADS + h) * 64 + d) * SEQ + s]) =
                    *reinterpret_cast<u64*>(t4);
            }
        }
    }
}

// ---------------------------------------------------------------------------
// Output GEMM, pipelined, 8-wave: ctx[4096][1024] @ Wo^T + bo, fp32 out.
// Same template (512 thr, 2Mx4N, vmcnt(2), 48KB 3-buf). Grid 256 = 1/CU.
// No setprio.
// ---------------------------------------------------------------------------
__global__ __launch_bounds__(512, 2)
void gemm_out_kernel(const u16* __restrict__ A, const u16* __restrict__ B,
                     const float* __restrict__ bias, float* __restrict__ out)
{
    __shared__ u16 Al[3][128 * 32];   // 3 x 8 KB
    __shared__ u16 Bl[3][128 * 32];   // 3 x 8 KB

    const int tid = threadIdx.x;
    const int l = tid & 63;
    const int w = tid >> 6;            // 0..7
    const int wm = w >> 2, wn = w & 3; // 2M x 4N
    const int lr = l & 15, lg = l >> 4;

    const int bid = blockIdx.x;                    // 0..255, 256%8==0
    const int swz = (bid & 7) * 32 + (bid >> 3);   // XCD-bijective
    const int mb = swz >> 3, nb = swz & 7;         // 32 x 8 blocks
    const int m0 = mb * 128, n0 = nb * 128;

    const int arow = tid >> 2;                               // 0..127
    const int acol = ((tid & 3) ^ ((arow >> 1) & 3)) * 8;
    const int dstq = tid * 8;                                // u16 units
    const int rsw  = (lr >> 1) & 3;

    f32x4 acc[4][2];
    #pragma unroll
    for (int i = 0; i < 4; ++i)
        #pragma unroll
        for (int j = 0; j < 2; ++j) acc[i][j] = (f32x4){0.f, 0.f, 0.f, 0.f};

    #pragma unroll
    for (int t = 0; t < 2; ++t) {
        const int k0 = t * 32;
        GLOAD16(A + (size_t)(m0 + arow) * D_MODEL + k0 + acol, &Al[t][dstq]);
        GLOAD16(B + (size_t)(n0 + arow) * D_MODEL + k0 + acol, &Bl[t][dstq]);
    }

    int cb = 0;
    for (int t = 0; t < 32; ++t) {
        if (t < 31) asm volatile("s_waitcnt vmcnt(2)" ::: "memory");
        else        asm volatile("s_waitcnt vmcnt(0)" ::: "memory");
        __builtin_amdgcn_s_barrier();

        if (t + 2 < 32) {
            const int sb = (cb >= 1) ? cb - 1 : cb + 2;   // (t+2)%3
            const int k0 = (t + 2) * 32;
            GLOAD16(A + (size_t)(m0 + arow) * D_MODEL + k0 + acol, &Al[sb][dstq]);
            GLOAD16(B + (size_t)(n0 + arow) * D_MODEL + k0 + acol, &Bl[sb][dstq]);
        }

        const u16* __restrict__ Ab = Al[cb];
        const u16* __restrict__ Bb = Bl[cb];
        bf16x8 af[4], bfr[2];
        #pragma unroll
        for (int i = 0; i < 4; ++i)
            af[i] = *reinterpret_cast<const bf16x8*>(
                &Ab[(wm * 64 + i * 16 + lr) * 32 + ((lg ^ rsw) * 8)]);
        #pragma unroll
        for (int j = 0; j < 2; ++j)
            bfr[j] = *reinterpret_cast<const bf16x8*>(
                &Bb[(wn * 32 + j * 16 + lr) * 32 + ((lg ^ rsw) * 8)]);

        #pragma unroll
        for (int i = 0; i < 4; ++i)
            #pragma unroll
            for (int j = 0; j < 2; ++j)
                acc[i][j] = __builtin_amdgcn_mfma_f32_16x16x32_bf16(
                    af[i], bfr[j], acc[i][j], 0, 0, 0);

        cb = (cb == 2) ? 0 : cb + 1;
    }

    #pragma unroll
    for (int i = 0; i < 4; ++i) {
        #pragma unroll
        for (int r = 0; r < 4; ++r) {
            const int m = m0 + wm * 64 + i * 16 + lg * 4 + r;
            #pragma unroll
            for (int j = 0; j < 2; ++j) {
                const int c = n0 + wn * 32 + j * 16 + lr;
                out[(size_t)m * D_MODEL + c] = acc[i][j][r] + bias[c];
            }
        }
    }
}

// ---------------------------------------------------------------------------
// Split-S MFMA causal flash attention, QBLK=128 (best measured version),
// no setprio. One barrier/tile, double-buffered 32KB LDS, split-S.
// ---------------------------------------------------------------------------
__device__ __forceinline__ void map_pair128(int p, int& qt2, int& ch) {
    if (p < 16)      { qt2 = 15 - (p >> 2); ch = p & 3; }
    else if (p < 28) { int t = p - 16; qt2 = 11 - t / 3; ch = t % 3; }
    else if (p < 36) { int t = p - 28; qt2 = 7 - (t >> 1); ch = t & 1; }
    else             { qt2 = 39 - p; ch = 0; }
}

__global__ __launch_bounds__(256)
void attn_kernel(const u16* __restrict__ Q, const u16* __restrict__ K,
                 const u16* __restrict__ Vt, u16* __restrict__ ctx,
                 u16* __restrict__ Opart, float* __restrict__ Lpart)
{
    __shared__ char LdsB[2][16384];   // per buf: K 8KB @0, V 8KB @8192

    const int tid = threadIdx.x;
    const int l = tid & 63;
    const int w = tid >> 6;
    const int lr = l & 15;
    const int lg = l >> 4;

    const int xcd  = blockIdx.x & 7;
    const int slot = blockIdx.x >> 3;          // 0..159
    const int bh   = xcd * 4 + slot / 40;      // 4 heads per XCD chunk
    int qt2, ch;
    map_pair128(slot % 40, qt2, ch);

    const int ntiles = 2 * qt2 + 2;
    const int nch  = (ntiles + 7) >> 3;        // ceil(ntiles/8)
    const int base = ntiles / nch, rem = ntiles % nch;
    const int start = ch * base + (ch < rem ? ch : rem);
    const int cnt   = base + (ch < rem ? 1 : 0);

    const size_t hbase = (size_t)bh * SEQ * 64;
    const int b = bh >> 4, h = bh & (NUM_HEADS - 1);
    const u16* __restrict__ Kh = K + hbase;
    const u16* __restrict__ Vh = Vt + hbase;
    const int q0 = qt2 * 128;

    const int r0 = tid >> 3;
    const int c0 = ((tid & 7) ^ (r0 & 7)) * 8;
    const int r1 = (256 + tid) >> 3;
    const int c1 = ((tid & 7) ^ (r1 & 7)) * 8;
    const int d0b = tid * 16;
    const int d1b = 4096 + tid * 16;
    const int rswz = (lr & 7) << 4;

    bf16x8 qf[2][2];
    #pragma unroll
    for (int fq = 0; fq < 2; ++fq) {
        const u16* qp = Q + hbase + (size_t)(q0 + fq * 64 + w * 16 + lr) * 64 + lg * 8;
        qf[fq][0] = *reinterpret_cast<const bf16x8*>(qp);
        qf[fq][1] = *reinterpret_cast<const bf16x8*>(qp + 32);
    }
    asm volatile("s_waitcnt vmcnt(0)" ::: "memory");   // keep stage-FIFO math exact

    f32x4 acc[2][4];
    #pragma unroll
    for (int fq = 0; fq < 2; ++fq)
        #pragma unroll
        for (int nb = 0; nb < 4; ++nb) acc[fq][nb] = (f32x4){0.f, 0.f, 0.f, 0.f};
    float lsumv[2] = {0.f, 0.f};

    {   // prologue: stage tile `start` -> buf 0 (4 loads in flight)
        char* kb = LdsB[0];
        char* vb = LdsB[0] + 8192;
        const int kb64 = start * 64;
        GLOAD16(Kh + (size_t)(kb64 + r0) * 64 + c0, kb + d0b);
        GLOAD16(Kh + (size_t)(kb64 + r1) * 64 + c1, kb + d1b);
        GLOAD16(Vh + (size_t)r0 * SEQ + kb64 + c0, vb + d0b);
        GLOAD16(Vh + (size_t)r1 * SEQ + kb64 + c1, vb + d1b);
    }

    for (int it = 0; it < cnt; ++it) {
        const int tile = start + it;
        const int buf = it & 1;

        // single per-tile checkpoint: tile `it` ready, publish to all waves
        asm volatile("s_waitcnt vmcnt(0)" ::: "memory");
        __builtin_amdgcn_s_barrier();

        if (it < cnt - 1) {                      // issue next tile's DMA now
            const int kb64 = (tile + 1) * 64;
            char* kbl = LdsB[buf ^ 1];
            char* vbl = kbl + 8192;
            GLOAD16(Kh + (size_t)(kb64 + r0) * 64 + c0, kbl + d0b);
            GLOAD16(Kh + (size_t)(kb64 + r1) * 64 + c1, kbl + d1b);
            GLOAD16(Vh + (size_t)r0 * SEQ + kb64 + c0, vbl + d0b);
            GLOAD16(Vh + (size_t)r1 * SEQ + kb64 + c1, vbl + d1b);
        }

        const char* kbuf = LdsB[buf];
        const char* vbuf = kbuf + 8192;

        bf16x8 kf[4][2];
        #pragma unroll
        for (int m = 0; m < 4; ++m) {
            const char* krow = kbuf + (16 * m + lr) * 128;
            kf[m][0] = *reinterpret_cast<const bf16x8*>(krow + ((lg * 16) ^ rswz));
            kf[m][1] = *reinterpret_cast<const bf16x8*>(krow + ((64 + lg * 16) ^ rswz));
        }

        const bool diag = (tile >= 2 * qt2);
        const int koff0 = (tile - 2 * qt2) * 64;

        unsigned dw[2][4][2];
        #pragma unroll
        for (int fq = 0; fq < 2; ++fq) {
            f32x4 s[4];
            #pragma unroll
            for (int m = 0; m < 4; ++m) {
                s[m] = (f32x4){0.f, 0.f, 0.f, 0.f};
                s[m] = __builtin_amdgcn_mfma_f32_16x16x32_bf16(kf[m][0], qf[fq][0], s[m], 0, 0, 0);
                s[m] = __builtin_amdgcn_mfma_f32_16x16x32_bf16(kf[m][1], qf[fq][1], s[m], 0, 0, 0);
            }
            if (diag) {
                const int qloc = fq * 64 + w * 16 + lr;
                #pragma unroll
                for (int m = 0; m < 4; ++m)
                    #pragma unroll
                    for (int r = 0; r < 4; ++r)
                        if (koff0 + 16 * m + 4 * lg + r > qloc) s[m][r] = -1.0e38f;
            }
            float p[4][4];
            #pragma unroll
            for (int m = 0; m < 4; ++m) {
                #pragma unroll
                for (int r = 0; r < 4; ++r) p[m][r] = EXP2(s[m][r]);
                lsumv[fq] += (p[m][0] + p[m][1]) + (p[m][2] + p[m][3]);
                dw[fq][m][0] = cvt_pk_bf16(p[m][0], p[m][1]);
                dw[fq][m][1] = cvt_pk_bf16(p[m][2], p[m][3]);
            }
        }

        #pragma unroll
        for (int c = 0; c < 2; ++c) {
            union Pu { unsigned u[4]; bf16x8 v; } pb[2];
            #pragma unroll
            for (int fq = 0; fq < 2; ++fq) {
                pb[fq].u[0] = dw[fq][2 * c][0];     pb[fq].u[1] = dw[fq][2 * c][1];
                pb[fq].u[2] = dw[fq][2 * c + 1][0]; pb[fq].u[3] = dw[fq][2 * c + 1][1];
            }
            #pragma unroll
            for (int nb = 0; nb < 4; ++nb) {
                const char* vrow = vbuf + (16 * nb + lr) * 128;
                union Vu { s16x4 hv[2]; bf16x8 v; } vf;
                vf.hv[0] = *reinterpret_cast<const s16x4*>(
                    vrow + ((c * 64 + lg * 8) ^ rswz));
                vf.hv[1] = *reinterpret_cast<const s16x4*>(
                    vrow + ((c * 64 + 32 + lg * 8) ^ rswz));
                acc[0][nb] = __builtin_amdgcn_mfma_f32_16x16x32_bf16(
                    vf.v, pb[0].v, acc[0][nb], 0, 0, 0);
                acc[1][nb] = __builtin_amdgcn_mfma_f32_16x16x32_bf16(
                    vf.v, pb[1].v, acc[1][nb], 0, 0, 0);
            }
        }
        // no end-of-tile barrier (next top barrier covers WAR on buf^1)
    }

    #pragma unroll
    for (int fq = 0; fq < 2; ++fq) {
        lsumv[fq] += __shfl_xor(lsumv[fq], 16);
        lsumv[fq] += __shfl_xor(lsumv[fq], 32);
    }

    if (nch == 1) {
        #pragma unroll
        for (int fq = 0; fq < 2; ++fq) {
            const float inv = 1.0f / lsumv[fq];
            const int qrow = q0 + fq * 64 + w * 16 + lr;
            u16* op = ctx + ((size_t)(b * SEQ) + qrow) * D_MODEL + h * 64 + 4 * lg;
            #pragma unroll
            for (int nb = 0; nb < 4; ++nb) {
                u16 t4[4];
                #pragma unroll
                for (int r = 0; r < 4; ++r) t4[r] = f2bf(acc[fq][nb][r] * inv);
                *reinterpret_cast<u64*>(op + 16 * nb) = *reinterpret_cast<u64*>(t4);
            }
        }
    } else {
        const int slot4 = ((bh * 12 + (qt2 - 4)) << 2) + ch;
        #pragma unroll
        for (int fq = 0; fq < 2; ++fq) {
            const int rloc = fq * 64 + w * 16 + lr;
            u16* op = Opart + (size_t)slot4 * 8192 + rloc * 64 + 4 * lg;
            #pragma unroll
            for (int nb = 0; nb < 4; ++nb) {
                u16 t4[4];
                #pragma unroll
                for (int r = 0; r < 4; ++r) t4[r] = f2bf(acc[fq][nb][r]);
                *reinterpret_cast<u64*>(op + 16 * nb) = *reinterpret_cast<u64*>(t4);
            }
            if (lg == 0) Lpart[slot4 * 128 + rloc] = lsumv[fq];
        }
    }
}

// Sum partials (<=4) for each (bh, qt2>=4), normalize, write ctx.
__global__ __launch_bounds__(128)
void attn_reduce_kernel(const u16* __restrict__ Opart,
                        const float* __restrict__ Lpart,
                        u16* __restrict__ ctx)
{
    const int blk = blockIdx.x;          // 0..383
    const int bh = blk / 12, idx = blk % 12;
    const int qt2 = idx + 4;
    const int nch = (2 * qt2 + 2 + 7) >> 3;
    const int t = threadIdx.x;           // query row in 128-tile
    const int b = bh >> 4, h = bh & (NUM_HEADS - 1);
    const int slot0 = (bh * 12 + idx) << 2;

    float acc[64] = {};
    float lt = 0.f;
    for (int ch = 0; ch < nch; ++ch) {
        const u16* op = Opart + (size_t)(slot0 + ch) * 8192 + t * 64;
        lt += Lpart[(slot0 + ch) * 128 + t];
        #pragma unroll
        for (int cchunk = 0; cchunk < 8; ++cchunk) {
            u16 v[8];
            *reinterpret_cast<int4*>(v) =
                *reinterpret_cast<const int4*>(op + cchunk * 8);
            #pragma unroll
            for (int j = 0; j < 8; ++j) acc[cchunk * 8 + j] += bf2f(v[j]);
        }
    }
    const float inv = 1.0f / lt;
    u16* orow = ctx + ((size_t)(b * SEQ) + qt2 * 128 + t) * D_MODEL + h * 64;
    #pragma unroll
    for (int cchunk = 0; cchunk < 8; ++cchunk) {
        u16 v[8];
        #pragma unroll
        for (int j = 0; j < 8; ++j) v[j] = f2bf(acc[cchunk * 8 + j] * inv);
        *reinterpret_cast<int4*>(orow + cchunk * 8) = *reinterpret_cast<int4*>(v);
    }
}

// ---------------------------------------------------------------------------

extern "C" void kernel_launch(void* const* d_in, const int* in_sizes, int n_in,
                              void* d_out, int out_size, void* d_ws, size_t ws_size,
                              hipStream_t stream)
{
    const float* x  = (const float*)d_in[0];
    const float* Wq = (const float*)d_in[1];
    const float* Wk = (const float*)d_in[2];
    const float* Wv = (const float*)d_in[3];
    const float* Wo = (const float*)d_in[4];
    const float* bo = (const float*)d_in[5];
    float* out = (float*)d_out;

    u16* xb   = (u16*)d_ws;                               // 4096*1024
    u16* wqkv = xb   + (size_t)MTOT * D_MODEL;            // 3072*1024
    u16* wob  = wqkv + (size_t)3 * D_MODEL * D_MODEL;     // 1024*1024
    u16* Qw   = wob  + (size_t)D_MODEL * D_MODEL;         // [b,h,s,d] (pre-scaled)
    u16* Kw   = Qw   + (size_t)MTOT * D_MODEL;            // [b,h,s,d]
    u16* Vtw  = Kw   + (size_t)MTOT * D_MODEL;            // [b,h,d,s]
    u16* ctxb = Vtw  + (size_t)MTOT * D_MODEL;            // [4096][1024]
    u16* Opart = ctxb + (size_t)MTOT * D_MODEL;           // 1536 slots x 8192
    float* Lpart = (float*)(Opart + (size_t)1536 * 8192); // 1536 x 128

    cast_all_kernel<<<4096, 256, 0, stream>>>(x, Wq, Wk, Wv, Wo, xb);

    gemm_qkv_kernel<<<dim3(768), 512, 0, stream>>>(xb, wqkv, Qw, Kw, Vtw);

    attn_kernel<<<dim3(1280), 256, 0, stream>>>(Qw, Kw, Vtw, ctxb, Opart, Lpart);
    attn_reduce_kernel<<<dim3(384), 128, 0, stream>>>(Opart, Lpart, ctxb);

    gemm_out_kernel<<<dim3(256), 512, 0, stream>>>(ctxb, wob, bo, out);
}